// Round 2
// baseline (840.172 us; speedup 1.0000x reference)
//
#include <hip/hip_runtime.h>
#include <hip/hip_bf16.h>

#define C 64
#define H 128
#define FEPS 1e-7f
#define BNE 1e-5f

__device__ __forceinline__ float wave_sum(float v) {
#pragma unroll
    for (int m = 32; m > 0; m >>= 1) v += __shfl_xor(v, m, 64);
    return v;
}

// ---------------- CSR build ----------------
__global__ void hist_k(const int* __restrict__ dst, int* __restrict__ counts, int E) {
    int i = blockIdx.x * 256 + threadIdx.x;
    if (i < E) atomicAdd(&counts[dst[i]], 1);
}

__global__ void scan1_k(const int* __restrict__ counts, int* __restrict__ rs,
                        int* __restrict__ partials, int N) {
    __shared__ int s[256];
    int i = blockIdx.x * 256 + threadIdx.x;
    int v = (i < N) ? counts[i] : 0;
    s[threadIdx.x] = v;
    __syncthreads();
    for (int off = 1; off < 256; off <<= 1) {
        int t = 0;
        if (threadIdx.x >= off) t = s[threadIdx.x - off];
        __syncthreads();
        s[threadIdx.x] += t;
        __syncthreads();
    }
    if (i < N) rs[i] = s[threadIdx.x] - v;      // block-local exclusive
    if (threadIdx.x == 255) partials[blockIdx.x] = s[255];
}

__global__ void scan2_k(int* __restrict__ partials, int nb) {
    __shared__ int s[1024];
    int v = (threadIdx.x < nb) ? partials[threadIdx.x] : 0;
    s[threadIdx.x] = v;
    __syncthreads();
    for (int off = 1; off < 1024; off <<= 1) {
        int t = 0;
        if (threadIdx.x >= off) t = s[threadIdx.x - off];
        __syncthreads();
        s[threadIdx.x] += t;
        __syncthreads();
    }
    if (threadIdx.x < nb) partials[threadIdx.x] = s[threadIdx.x] - v;  // exclusive
}

__global__ void scan3_k(int* __restrict__ rs, const int* __restrict__ partials, int N, int E) {
    int i = blockIdx.x * 256 + threadIdx.x;
    if (i < N) rs[i] += partials[i >> 8];
    if (i == N) rs[N] = E;
}

__global__ void scatter_k(const int* __restrict__ src, const int* __restrict__ dst,
                          const int* __restrict__ rs, int* __restrict__ fill,
                          int* __restrict__ col, int E) {
    int i = blockIdx.x * 256 + threadIdx.x;
    if (i < E) {
        int d = dst[i];
        int pos = rs[d] + atomicAdd(&fill[d], 1);
        col[pos] = src[i];
    }
}

// ---------------- fused softmax-aggregation + MessageNorm ----------------
// MODE 0: input is raw x (identity transform)
// MODE 1: input is f32 y, transform v -> relu(v*a[c]+c[c]) + eps  (BN-apply + relu + eps)
template <int MODE>
__global__ __launch_bounds__(256) void agg_k(const float* __restrict__ xin,
                                             const float* __restrict__ ta,
                                             const float* __restrict__ tc,
                                             const int* __restrict__ rs,
                                             const int* __restrict__ col,
                                             const float* __restrict__ t,
                                             const float* __restrict__ sc,
                                             int layer, float* __restrict__ outb, int N) {
    int lane = threadIdx.x & 63;
    int wid = threadIdx.x >> 6;
    int n = blockIdx.x * 4 + wid;
    if (n >= N) return;
    float tv = t[layer];
    float sv = sc[layer];
    float aC = 1.f, cC = 0.f;
    if (MODE == 1) { aC = ta[lane]; cC = tc[lane]; }

    auto ldx = [&](int idx) -> float {
        float v = xin[idx];
        if (MODE == 1) v = fmaxf(v * aC + cC, 0.f) + FEPS;
        return v;
    };

    int beg = rs[n], end = rs[n + 1];
    float den = 0.f, num = 0.f;
    int e = beg;
    for (; e + 1 < end; e += 2) {
        int s0 = col[e], s1 = col[e + 1];
        float x0 = ldx(s0 * C + lane);
        float x1 = ldx(s1 * C + lane);
        float m0 = fmaxf(x0, 0.f) + FEPS;
        float m1 = fmaxf(x1, 0.f) + FEPS;
        float e0 = __expf(m0 * tv);
        float e1 = __expf(m1 * tv);
        den += e0; num += m0 * e0;
        den += e1; num += m1 * e1;
    }
    if (e < end) {
        int s0 = col[e];
        float x0 = ldx(s0 * C + lane);
        float m0 = fmaxf(x0, 0.f) + FEPS;
        float e0 = __expf(m0 * tv);
        den += e0; num += m0 * e0;
    }
    float agg = (den > 0.f) ? (num / den) : 0.f;
    float na = wave_sum(agg * agg);
    float xn = ldx(n * C + lane);
    float nx = wave_sum(xn * xn);
    float inv = 1.0f / fmaxf(sqrtf(na), 1e-12f);
    outb[n * C + lane] = xn + agg * inv * sqrtf(nx) * sv;
}

// ---------------- MLP GEMM1: h = out @ W1 + b1, + column stats of h ----------------
__global__ __launch_bounds__(256) void mlp1_k(const float* __restrict__ outb,
                                              const float* __restrict__ W1,
                                              const float* __restrict__ b1,
                                              float* __restrict__ h,
                                              float* __restrict__ s_sum,
                                              float* __restrict__ s_ssq, int N) {
    __shared__ float W[C * H];
    __shared__ float red[4][H][2];
    int tid = threadIdx.x;
    int lane = tid & 63, wid = tid >> 6;
    for (int i = tid; i < C * H / 4; i += 256)
        ((float4*)W)[i] = ((const float4*)W1)[i];
    float bb0 = b1[lane], bb1 = b1[lane + 64];
    __syncthreads();
    float s0 = 0.f, q0 = 0.f, s1 = 0.f, q1 = 0.f;
    int nw = gridDim.x * 4;
    for (int r = blockIdx.x * 4 + wid; r < N; r += nw) {
        float o = outb[r * C + lane];
        float h0 = bb0, h1 = bb1;
#pragma unroll
        for (int k = 0; k < 64; k++) {
            float a = __shfl(o, k, 64);
            h0 += a * W[k * H + lane];
            h1 += a * W[k * H + 64 + lane];
        }
        h[r * H + lane] = h0;
        h[r * H + 64 + lane] = h1;
        s0 += h0; q0 += h0 * h0;
        s1 += h1; q1 += h1 * h1;
    }
    red[wid][lane][0] = s0; red[wid][lane][1] = q0;
    red[wid][lane + 64][0] = s1; red[wid][lane + 64][1] = q1;
    __syncthreads();
    if (tid < H) {
        float ts = 0.f, tq = 0.f;
        for (int w = 0; w < 4; w++) { ts += red[w][tid][0]; tq += red[w][tid][1]; }
        atomicAdd(&s_sum[tid], ts);
        atomicAdd(&s_ssq[tid], tq);
    }
}

// ---------------- BN finalize: a = rsig*g ; c = b - mu*rsig*g ----------------
__global__ void bnfin_k(const float* __restrict__ sum, const float* __restrict__ ssq,
                        const float* __restrict__ g, const float* __restrict__ b,
                        float* __restrict__ a, float* __restrict__ cc, int n, float invN) {
    int i = threadIdx.x;
    if (i < n) {
        float mu = sum[i] * invN;
        float var = ssq[i] * invN - mu * mu;
        float rs = rsqrtf(var + BNE);
        float gg = g[i];
        float bb = b[i];
        a[i] = rs * gg;
        cc[i] = bb - mu * rs * gg;
    }
}

// ---------------- MLP GEMM2: y = relu(h*a1+c1) @ W2 + b2, + column stats of y ----------------
__global__ __launch_bounds__(256) void mlp2_k(const float* __restrict__ h,
                                              const float* __restrict__ a1,
                                              const float* __restrict__ c1,
                                              const float* __restrict__ W2,
                                              const float* __restrict__ b2,
                                              float* __restrict__ y,
                                              float* __restrict__ s_sum,
                                              float* __restrict__ s_ssq, int N) {
    __shared__ float W[H * C];
    __shared__ float red[4][C][2];
    int tid = threadIdx.x;
    int lane = tid & 63, wid = tid >> 6;
    for (int i = tid; i < H * C / 4; i += 256)
        ((float4*)W)[i] = ((const float4*)W2)[i];
    float bb = b2[lane];
    float ai0 = a1[lane], ci0 = c1[lane];
    float ai1 = a1[lane + 64], ci1 = c1[lane + 64];
    __syncthreads();
    float s = 0.f, q = 0.f;
    int nw = gridDim.x * 4;
    for (int r = blockIdx.x * 4 + wid; r < N; r += nw) {
        float hh0 = h[r * H + lane];
        float hh1 = h[r * H + 64 + lane];
        float g0 = fmaxf(hh0 * ai0 + ci0, 0.f);
        float g1 = fmaxf(hh1 * ai1 + ci1, 0.f);
        float acc = bb;
#pragma unroll
        for (int j = 0; j < 64; j++) {
            float a = __shfl(g0, j, 64);
            acc += a * W[j * C + lane];
        }
#pragma unroll
        for (int j = 0; j < 64; j++) {
            float a = __shfl(g1, j, 64);
            acc += a * W[(64 + j) * C + lane];
        }
        y[r * C + lane] = acc;
        s += acc; q += acc * acc;
    }
    red[wid][lane][0] = s; red[wid][lane][1] = q;
    __syncthreads();
    if (tid < C) {
        float ts = 0.f, tq = 0.f;
        for (int w = 0; w < 4; w++) { ts += red[w][tid][0]; tq += red[w][tid][1]; }
        atomicAdd(&s_sum[tid], ts);
        atomicAdd(&s_ssq[tid], tq);
    }
}

// ---------------- final: out = relu(x0 + (y*a2+c2)) + eps ----------------
__global__ void final_k(const float* __restrict__ x0, const float* __restrict__ y,
                        const float* __restrict__ a2, const float* __restrict__ c2,
                        float* __restrict__ outp, int total) {
    int i = blockIdx.x * 256 + threadIdx.x;
    if (i < total) {
        int c = i & 63;
        float v = y[i] * a2[c] + c2[c];
        float r = fmaxf(x0[i] + v, 0.f) + FEPS;
        outp[i] = r;
    }
}

extern "C" void kernel_launch(void* const* d_in, const int* in_sizes, int n_in,
                              void* d_out, int out_size, void* d_ws, size_t ws_size,
                              hipStream_t stream) {
    const float* x0 = (const float*)d_in[0];
    const int* ei = (const int*)d_in[1];
    const float* t = (const float*)d_in[2];
    const float* scale = (const float*)d_in[3];
    const float* W1 = (const float*)d_in[4];
    const float* b1 = (const float*)d_in[5];
    const float* g1 = (const float*)d_in[6];
    const float* be1 = (const float*)d_in[7];
    const float* W2 = (const float*)d_in[8];
    const float* b2 = (const float*)d_in[9];
    const float* bn_g = (const float*)d_in[10];
    const float* bn_b = (const float*)d_in[11];

    const int N = in_sizes[0] / C;
    const int E = in_sizes[1] / 2;
    const int* src = ei;
    const int* dst = ei + E;

    char* ws = (char*)d_ws;
    size_t cur = 0;
    auto alloc = [&](size_t bytes) -> char* {
        char* p = ws + cur;
        cur = (cur + bytes + 255) & ~(size_t)255;
        return p;
    };
    int* counts = (int*)alloc((size_t)N * 4);
    int* fill = (int*)alloc((size_t)N * 4);
    float* stats = (float*)alloc(768 * 4);          // [layer][sum1 128|ssq1 128|sum2 64|ssq2 64]
    size_t zbytes = cur;                            // zero everything above each call
    float* params = (float*)alloc(768 * 4);         // [layer][a1 128|c1 128|a2 64|c2 64]
    int* partials = (int*)alloc(1024 * 4);
    int* row_start = (int*)alloc(((size_t)N + 1) * 4);
    int* col = (int*)alloc((size_t)E * 4);
    float* bout = (float*)alloc((size_t)N * C * 4);
    float* bh = (float*)alloc((size_t)N * H * 4);
    float* by = (float*)alloc((size_t)N * C * 4);

    hipMemsetAsync(d_ws, 0, zbytes, stream);

    // CSR build
    int nbE = (E + 255) / 256;
    int nb1 = (N + 255) / 256;
    hist_k<<<nbE, 256, 0, stream>>>(dst, counts, E);
    scan1_k<<<nb1, 256, 0, stream>>>(counts, row_start, partials, N);
    scan2_k<<<1, 1024, 0, stream>>>(partials, nb1);
    int nb3 = (N + 256) / 256;
    scan3_k<<<nb3, 256, 0, stream>>>(row_start, partials, N, E);
    scatter_k<<<nbE, 256, 0, stream>>>(src, dst, row_start, fill, col, E);

    float* sum1_0 = stats + 0;   float* ssq1_0 = stats + 128;
    float* sum2_0 = stats + 256; float* ssq2_0 = stats + 320;
    float* sum1_1 = stats + 384; float* ssq1_1 = stats + 512;
    float* sum2_1 = stats + 640; float* ssq2_1 = stats + 704;
    float* a1_0 = params + 0;   float* c1_0 = params + 128;
    float* a2_0 = params + 256; float* c2_0 = params + 320;
    float* a1_1 = params + 384; float* c1_1 = params + 512;
    float* a2_1 = params + 640; float* c2_1 = params + 704;

    const float invN = 1.0f / (float)N;
    int nbN4 = (N + 3) / 4;

    // ---- layer 0 ----
    agg_k<0><<<nbN4, 256, 0, stream>>>(x0, nullptr, nullptr, row_start, col, t, scale, 0, bout, N);
    mlp1_k<<<512, 256, 0, stream>>>(bout, W1, b1, bh, sum1_0, ssq1_0, N);
    bnfin_k<<<1, 128, 0, stream>>>(sum1_0, ssq1_0, g1, be1, a1_0, c1_0, H, invN);
    mlp2_k<<<512, 256, 0, stream>>>(bh, a1_0, c1_0, W2, b2, by, sum2_0, ssq2_0, N);
    bnfin_k<<<1, 64, 0, stream>>>(sum2_0, ssq2_0, bn_g, bn_b, a2_0, c2_0, C, invN);

    // ---- layer 1 (reads y0 with fused BN+relu+eps transform) ----
    agg_k<1><<<nbN4, 256, 0, stream>>>(by, a2_0, c2_0, row_start, col, t, scale, 1, bout, N);
    mlp1_k<<<512, 256, 0, stream>>>(bout, W1 + C * H, b1 + H, bh, sum1_1, ssq1_1, N);
    bnfin_k<<<1, 128, 0, stream>>>(sum1_1, ssq1_1, g1 + H, be1 + H, a1_1, c1_1, H, invN);
    mlp2_k<<<512, 256, 0, stream>>>(bh, a1_1, c1_1, W2 + H * C, b2 + C, by, sum2_1, ssq2_1, N);
    bnfin_k<<<1, 64, 0, stream>>>(sum2_1, ssq2_1, bn_g + C, bn_b + C, a2_1, c2_1, C, invN);

    // ---- residual + relu + eps ----
    final_k<<<(N * C + 255) / 256, 256, 0, stream>>>(x0, by, a2_1, c2_1,
                                                     (float*)d_out, N * C);
}

// Round 4
// 664.365 us; speedup vs baseline: 1.2646x; 1.2646x over previous
//
#include <hip/hip_runtime.h>
#include <hip/hip_bf16.h>

#define C 64
#define H 128
#define FEPS 1e-7f
#define BNE 1e-5f

__device__ __forceinline__ float wave_sum(float v) {
#pragma unroll
    for (int m = 32; m > 0; m >>= 1) v += __shfl_xor(v, m, 64);
    return v;
}

// ---------------- CSR build ----------------
__global__ void hist_k(const int* __restrict__ dst, int* __restrict__ counts, int E) {
    int i = blockIdx.x * 256 + threadIdx.x;
    if (i < E) atomicAdd(&counts[dst[i]], 1);
}

__global__ void scan1_k(const int* __restrict__ counts, int* __restrict__ rs,
                        int* __restrict__ partials, int N) {
    __shared__ int s[256];
    int i = blockIdx.x * 256 + threadIdx.x;
    int v = (i < N) ? counts[i] : 0;
    s[threadIdx.x] = v;
    __syncthreads();
    for (int off = 1; off < 256; off <<= 1) {
        int t = 0;
        if (threadIdx.x >= off) t = s[threadIdx.x - off];
        __syncthreads();
        s[threadIdx.x] += t;
        __syncthreads();
    }
    if (i < N) rs[i] = s[threadIdx.x] - v;      // block-local exclusive
    if (threadIdx.x == 255) partials[blockIdx.x] = s[255];
}

__global__ void scan2_k(int* __restrict__ partials, int nb) {
    __shared__ int s[1024];
    int v = (threadIdx.x < nb) ? partials[threadIdx.x] : 0;
    s[threadIdx.x] = v;
    __syncthreads();
    for (int off = 1; off < 1024; off <<= 1) {
        int t = 0;
        if (threadIdx.x >= off) t = s[threadIdx.x - off];
        __syncthreads();
        s[threadIdx.x] += t;
        __syncthreads();
    }
    if (threadIdx.x < nb) partials[threadIdx.x] = s[threadIdx.x] - v;  // exclusive
}

__global__ void scan3_k(int* __restrict__ rs, const int* __restrict__ partials, int N, int E) {
    int i = blockIdx.x * 256 + threadIdx.x;
    if (i < N) rs[i] += partials[i >> 8];
    if (i == N) rs[N] = E;
}

__global__ void scatter_k(const int* __restrict__ src, const int* __restrict__ dst,
                          const int* __restrict__ rs, int* __restrict__ fill,
                          int* __restrict__ col, int E) {
    int i = blockIdx.x * 256 + threadIdx.x;
    if (i < E) {
        int d = dst[i];
        int pos = rs[d] + atomicAdd(&fill[d], 1);
        col[pos] = src[i];
    }
}

// ---------------- fused softmax-aggregation + MessageNorm ----------------
template <int MODE>
__global__ __launch_bounds__(256) void agg_k(const float* __restrict__ xin,
                                             const float* __restrict__ ta,
                                             const float* __restrict__ tc,
                                             const int* __restrict__ rs,
                                             const int* __restrict__ col,
                                             const float* __restrict__ t,
                                             const float* __restrict__ sc,
                                             int layer, float* __restrict__ outb, int N) {
    int lane = threadIdx.x & 63;
    int wid = threadIdx.x >> 6;
    int n = blockIdx.x * 4 + wid;
    if (n >= N) return;
    float tv = t[layer];
    float sv = sc[layer];
    float aC = 1.f, cC = 0.f;
    if (MODE == 1) { aC = ta[lane]; cC = tc[lane]; }

    auto ldx = [&](int idx) -> float {
        float v = xin[idx];
        if (MODE == 1) v = fmaxf(v * aC + cC, 0.f) + FEPS;
        return v;
    };

    int beg = rs[n], end = rs[n + 1];
    float den = 0.f, num = 0.f;
    int e = beg;
    for (; e + 1 < end; e += 2) {
        int s0 = col[e], s1 = col[e + 1];
        float x0 = ldx(s0 * C + lane);
        float x1 = ldx(s1 * C + lane);
        float m0 = fmaxf(x0, 0.f) + FEPS;
        float m1 = fmaxf(x1, 0.f) + FEPS;
        float e0 = __expf(m0 * tv);
        float e1 = __expf(m1 * tv);
        den += e0; num += m0 * e0;
        den += e1; num += m1 * e1;
    }
    if (e < end) {
        int s0 = col[e];
        float x0 = ldx(s0 * C + lane);
        float m0 = fmaxf(x0, 0.f) + FEPS;
        float e0 = __expf(m0 * tv);
        den += e0; num += m0 * e0;
    }
    float agg = (den > 0.f) ? (num / den) : 0.f;
    float na = wave_sum(agg * agg);
    float xn = ldx(n * C + lane);
    float nx = wave_sum(xn * xn);
    float inv = 1.0f / fmaxf(sqrtf(na), 1e-12f);
    outb[n * C + lane] = xn + agg * inv * sqrtf(nx) * sv;
}

// ---------------- tiled MLP GEMM: out[N,ND] = act(A[N,KD]) @ W[KD,ND] + bias ----------------
// AFF=1: A element (row,k) -> relu(A*fa[k]+fc[k])  (fused BN+relu of previous stage)
// Also accumulates column sum/sumsq of out into s_sum/s_ssq (for next BN).
template <int KD, int ND, int AFF>
__global__ __launch_bounds__(256) void mlp_k(const float* __restrict__ A,
                                             const float* __restrict__ fa,
                                             const float* __restrict__ fc,
                                             const float* __restrict__ Wg,
                                             const float* __restrict__ bias,
                                             float* __restrict__ outp,
                                             float* __restrict__ s_sum,
                                             float* __restrict__ s_ssq, int N) {
    constexpr int AST = KD + 4;           // padded A stride
    constexpr int NG = ND / 64;           // col groups of 4 per thread
    __shared__ float Ws[KD * ND];
    __shared__ float As[64 * AST];
    __shared__ float faf[AFF ? KD : 1][2];
    __shared__ float st[ND][2];

    int tid = threadIdx.x;
    // stage W (coalesced float4)
    for (int i = tid; i < KD * ND / 4; i += 256)
        ((float4*)Ws)[i] = ((const float4*)Wg)[i];
    if (AFF) {
        for (int i = tid; i < KD; i += 256) { faf[i][0] = fa[i]; faf[i][1] = fc[i]; }
    }
    if (tid < ND) { st[tid][0] = 0.f; st[tid][1] = 0.f; }
    __syncthreads();   // faf/st visible before A-tile staging uses them (round-3 race fix)

    // stage A tile (64 rows), fused affine+relu if AFF
    int base = blockIdx.x * 64;
    for (int e = tid; e < 64 * KD / 4; e += 256) {
        int row = e / (KD / 4);
        int kk = (e % (KD / 4)) * 4;
        float4 v = make_float4(0.f, 0.f, 0.f, 0.f);
        if (base + row < N) v = ((const float4*)A)[(size_t)(base + row) * (KD / 4) + (kk >> 2)];
        if (AFF) {
            v.x = fmaxf(v.x * faf[kk + 0][0] + faf[kk + 0][1], 0.f);
            v.y = fmaxf(v.y * faf[kk + 1][0] + faf[kk + 1][1], 0.f);
            v.z = fmaxf(v.z * faf[kk + 2][0] + faf[kk + 2][1], 0.f);
            v.w = fmaxf(v.w * faf[kk + 3][0] + faf[kk + 3][1], 0.f);
        }
        *(float4*)&As[row * AST + kk] = v;
    }
    __syncthreads();

    int ri = tid >> 4, ci = tid & 15;
    int r0 = ri * 4;
    float acc[4][NG][4];
#pragma unroll
    for (int j = 0; j < 4; j++)
#pragma unroll
        for (int g = 0; g < NG; g++)
#pragma unroll
            for (int c = 0; c < 4; c++) acc[j][g][c] = 0.f;

    for (int k4 = 0; k4 < KD / 4; k4++) {
        float av[4][4];
#pragma unroll
        for (int j = 0; j < 4; j++) {
            float4 t4 = *(const float4*)&As[(r0 + j) * AST + k4 * 4];
            av[j][0] = t4.x; av[j][1] = t4.y; av[j][2] = t4.z; av[j][3] = t4.w;
        }
#pragma unroll
        for (int kk = 0; kk < 4; kk++) {
            int k = k4 * 4 + kk;
#pragma unroll
            for (int g = 0; g < NG; g++) {
                float4 wv = *(const float4*)&Ws[k * ND + g * 64 + ci * 4];
#pragma unroll
                for (int j = 0; j < 4; j++) {
                    acc[j][g][0] += av[j][kk] * wv.x;
                    acc[j][g][1] += av[j][kk] * wv.y;
                    acc[j][g][2] += av[j][kk] * wv.z;
                    acc[j][g][3] += av[j][kk] * wv.w;
                }
            }
        }
    }

    // epilogue: bias, store, column stats
    float bb[NG][4];
#pragma unroll
    for (int g = 0; g < NG; g++) {
        float4 b4 = *(const float4*)&bias[g * 64 + ci * 4];
        bb[g][0] = b4.x; bb[g][1] = b4.y; bb[g][2] = b4.z; bb[g][3] = b4.w;
    }
    float ls[NG][4], lq[NG][4];
#pragma unroll
    for (int g = 0; g < NG; g++)
#pragma unroll
        for (int c = 0; c < 4; c++) { ls[g][c] = 0.f; lq[g][c] = 0.f; }

#pragma unroll
    for (int j = 0; j < 4; j++) {
        int row = base + r0 + j;
        if (row < N) {
#pragma unroll
            for (int g = 0; g < NG; g++) {
                float4 h4;
                h4.x = acc[j][g][0] + bb[g][0];
                h4.y = acc[j][g][1] + bb[g][1];
                h4.z = acc[j][g][2] + bb[g][2];
                h4.w = acc[j][g][3] + bb[g][3];
                *(float4*)&outp[(size_t)row * ND + g * 64 + ci * 4] = h4;
                ls[g][0] += h4.x; lq[g][0] += h4.x * h4.x;
                ls[g][1] += h4.y; lq[g][1] += h4.y * h4.y;
                ls[g][2] += h4.z; lq[g][2] += h4.z * h4.z;
                ls[g][3] += h4.w; lq[g][3] += h4.w * h4.w;
            }
        }
    }
#pragma unroll
    for (int g = 0; g < NG; g++)
#pragma unroll
        for (int c = 0; c < 4; c++) {
            atomicAdd(&st[g * 64 + ci * 4 + c][0], ls[g][c]);
            atomicAdd(&st[g * 64 + ci * 4 + c][1], lq[g][c]);
        }
    __syncthreads();
    if (tid < ND) {
        atomicAdd(&s_sum[tid], st[tid][0]);
        atomicAdd(&s_ssq[tid], st[tid][1]);
    }
}

// ---------------- BN finalize: a = rsig*g ; c = b - mu*rsig*g ----------------
__global__ void bnfin_k(const float* __restrict__ sum, const float* __restrict__ ssq,
                        const float* __restrict__ g, const float* __restrict__ b,
                        float* __restrict__ a, float* __restrict__ cc, int n, float invN) {
    int i = threadIdx.x;
    if (i < n) {
        float mu = sum[i] * invN;
        float var = ssq[i] * invN - mu * mu;
        float rs = rsqrtf(var + BNE);
        float gg = g[i];
        float bb = b[i];
        a[i] = rs * gg;
        cc[i] = bb - mu * rs * gg;
    }
}

// ---------------- final: out = relu(x0 + (y*a2+c2)) + eps ----------------
__global__ void final_k(const float* __restrict__ x0, const float* __restrict__ y,
                        const float* __restrict__ a2, const float* __restrict__ c2,
                        float* __restrict__ outp, int total) {
    int i = blockIdx.x * 256 + threadIdx.x;
    if (i < total) {
        int c = i & 63;
        float v = y[i] * a2[c] + c2[c];
        float r = fmaxf(x0[i] + v, 0.f) + FEPS;
        outp[i] = r;
    }
}

extern "C" void kernel_launch(void* const* d_in, const int* in_sizes, int n_in,
                              void* d_out, int out_size, void* d_ws, size_t ws_size,
                              hipStream_t stream) {
    const float* x0 = (const float*)d_in[0];
    const int* ei = (const int*)d_in[1];
    const float* t = (const float*)d_in[2];
    const float* scale = (const float*)d_in[3];
    const float* W1 = (const float*)d_in[4];
    const float* b1 = (const float*)d_in[5];
    const float* g1 = (const float*)d_in[6];
    const float* be1 = (const float*)d_in[7];
    const float* W2 = (const float*)d_in[8];
    const float* b2 = (const float*)d_in[9];
    const float* bn_g = (const float*)d_in[10];
    const float* bn_b = (const float*)d_in[11];

    const int N = in_sizes[0] / C;
    const int E = in_sizes[1] / 2;
    const int* src = ei;
    const int* dst = ei + E;

    char* ws = (char*)d_ws;
    size_t cur = 0;
    auto alloc = [&](size_t bytes) -> char* {
        char* p = ws + cur;
        cur = (cur + bytes + 255) & ~(size_t)255;
        return p;
    };
    int* counts = (int*)alloc((size_t)N * 4);
    int* fill = (int*)alloc((size_t)N * 4);
    float* stats = (float*)alloc(768 * 4);          // [layer][sum1 128|ssq1 128|sum2 64|ssq2 64]
    size_t zbytes = cur;                            // zero everything above each call
    float* params = (float*)alloc(768 * 4);         // [layer][a1 128|c1 128|a2 64|c2 64]
    int* partials = (int*)alloc(1024 * 4);
    int* row_start = (int*)alloc(((size_t)N + 1) * 4);
    int* col = (int*)alloc((size_t)E * 4);
    float* bout = (float*)alloc((size_t)N * C * 4);
    float* bh = (float*)alloc((size_t)N * H * 4);
    float* by = (float*)alloc((size_t)N * C * 4);

    hipMemsetAsync(d_ws, 0, zbytes, stream);

    // CSR build
    int nbE = (E + 255) / 256;
    int nb1 = (N + 255) / 256;
    hist_k<<<nbE, 256, 0, stream>>>(dst, counts, E);
    scan1_k<<<nb1, 256, 0, stream>>>(counts, row_start, partials, N);
    scan2_k<<<1, 1024, 0, stream>>>(partials, nb1);
    int nb3 = (N + 256) / 256;
    scan3_k<<<nb3, 256, 0, stream>>>(row_start, partials, N, E);
    scatter_k<<<nbE, 256, 0, stream>>>(src, dst, row_start, fill, col, E);

    float* sum1_0 = stats + 0;   float* ssq1_0 = stats + 128;
    float* sum2_0 = stats + 256; float* ssq2_0 = stats + 320;
    float* sum1_1 = stats + 384; float* ssq1_1 = stats + 512;
    float* sum2_1 = stats + 640; float* ssq2_1 = stats + 704;
    float* a1_0 = params + 0;   float* c1_0 = params + 128;
    float* a2_0 = params + 256; float* c2_0 = params + 320;
    float* a1_1 = params + 384; float* c1_1 = params + 512;
    float* a2_1 = params + 640; float* c2_1 = params + 704;

    const float invN = 1.0f / (float)N;
    int nbN4 = (N + 3) / 4;
    int nbT = (N + 63) / 64;   // GEMM row tiles

    // ---- layer 0 ----
    agg_k<0><<<nbN4, 256, 0, stream>>>(x0, nullptr, nullptr, row_start, col, t, scale, 0, bout, N);
    mlp_k<C, H, 0><<<nbT, 256, 0, stream>>>(bout, nullptr, nullptr, W1, b1, bh, sum1_0, ssq1_0, N);
    bnfin_k<<<1, 128, 0, stream>>>(sum1_0, ssq1_0, g1, be1, a1_0, c1_0, H, invN);
    mlp_k<H, C, 1><<<nbT, 256, 0, stream>>>(bh, a1_0, c1_0, W2, b2, by, sum2_0, ssq2_0, N);
    bnfin_k<<<1, 64, 0, stream>>>(sum2_0, ssq2_0, bn_g, bn_b, a2_0, c2_0, C, invN);

    // ---- layer 1 (agg reads y0 with fused BN+relu+eps transform) ----
    agg_k<1><<<nbN4, 256, 0, stream>>>(by, a2_0, c2_0, row_start, col, t, scale, 1, bout, N);
    mlp_k<C, H, 0><<<nbT, 256, 0, stream>>>(bout, nullptr, nullptr, W1 + C * H, b1 + H, bh, sum1_1, ssq1_1, N);
    bnfin_k<<<1, 128, 0, stream>>>(sum1_1, ssq1_1, g1 + H, be1 + H, a1_1, c1_1, H, invN);
    mlp_k<H, C, 1><<<nbT, 256, 0, stream>>>(bh, a1_1, c1_1, W2 + H * C, b2 + C, by, sum2_1, ssq2_1, N);
    bnfin_k<<<1, 64, 0, stream>>>(sum2_1, ssq2_1, bn_g + C, bn_b + C, a2_1, c2_1, C, invN);

    // ---- residual + relu + eps ----
    final_k<<<(N * C + 255) / 256, 256, 0, stream>>>(x0, by, a2_1, c2_1,
                                                     (float*)d_out, N * C);
}

// Round 5
// 630.564 us; speedup vs baseline: 1.3324x; 1.0536x over previous
//
#include <hip/hip_runtime.h>
#include <hip/hip_bf16.h>

#define C 64
#define H 128
#define FEPS 1e-7f
#define BNE 1e-5f

__device__ __forceinline__ float b2f(__hip_bfloat16 v) { return __bfloat162float(v); }

__device__ __forceinline__ float wave_sum(float v) {
#pragma unroll
    for (int m = 32; m > 0; m >>= 1) v += __shfl_xor(v, m, 64);
    return v;
}

// ---------------- CSR build ----------------
__global__ void hist_k(const int* __restrict__ dst, int* __restrict__ counts, int E) {
    int i = blockIdx.x * 256 + threadIdx.x;
    if (i < E) atomicAdd(&counts[dst[i]], 1);
}

__global__ void scan1_k(const int* __restrict__ counts, int* __restrict__ rs,
                        int* __restrict__ partials, int N) {
    __shared__ int s[256];
    int i = blockIdx.x * 256 + threadIdx.x;
    int v = (i < N) ? counts[i] : 0;
    s[threadIdx.x] = v;
    __syncthreads();
    for (int off = 1; off < 256; off <<= 1) {
        int t = 0;
        if (threadIdx.x >= off) t = s[threadIdx.x - off];
        __syncthreads();
        s[threadIdx.x] += t;
        __syncthreads();
    }
    if (i < N) rs[i] = s[threadIdx.x] - v;      // block-local exclusive
    if (threadIdx.x == 255) partials[blockIdx.x] = s[255];
}

__global__ void scan2_k(int* __restrict__ partials, int nb) {
    __shared__ int s[1024];
    int v = (threadIdx.x < nb) ? partials[threadIdx.x] : 0;
    s[threadIdx.x] = v;
    __syncthreads();
    for (int off = 1; off < 1024; off <<= 1) {
        int t = 0;
        if (threadIdx.x >= off) t = s[threadIdx.x - off];
        __syncthreads();
        s[threadIdx.x] += t;
        __syncthreads();
    }
    if (threadIdx.x < nb) partials[threadIdx.x] = s[threadIdx.x] - v;  // exclusive
}

__global__ void scan3_k(int* __restrict__ rs, const int* __restrict__ partials, int N, int E) {
    int i = blockIdx.x * 256 + threadIdx.x;
    if (i < N) rs[i] += partials[i >> 8];
    if (i == N) rs[N] = E;
}

__global__ void scatter_k(const int* __restrict__ src, const int* __restrict__ dst,
                          const int* __restrict__ rs, int* __restrict__ fill,
                          int* __restrict__ col, int E) {
    int i = blockIdx.x * 256 + threadIdx.x;
    if (i < E) {
        int d = dst[i];
        int pos = rs[d] + atomicAdd(&fill[d], 1);
        col[pos] = src[i];
    }
}

// ---------------- message prep: marr = bf16(relu(x)+eps), x possibly BN-affined ----------------
// AFF=0: in = x0            -> m = relu(v)+eps
// AFF=1: in = y (pre-BN)    -> x = relu(v*fa[c]+fc[c])+eps ; m = relu(x)+eps = x+eps
template <int AFF>
__global__ __launch_bounds__(256) void prep_k(const float* __restrict__ in,
                                              const float* __restrict__ fa,
                                              const float* __restrict__ fc,
                                              ushort* __restrict__ marr, int total4) {
    int i = blockIdx.x * 256 + threadIdx.x;
    if (i >= total4) return;
    float4 v = ((const float4*)in)[i];
    int c0 = (i * 4) & 63;
    float vv[4] = {v.x, v.y, v.z, v.w};
    ushort u[4];
#pragma unroll
    for (int j = 0; j < 4; j++) {
        float x = vv[j];
        if (AFF) {
            float xv = fmaxf(x * fa[c0 + j] + fc[c0 + j], 0.f) + FEPS;
            x = xv + FEPS;
        } else {
            x = fmaxf(x, 0.f) + FEPS;
        }
        __hip_bfloat16 h = __float2bfloat16(x);
        u[j] = *reinterpret_cast<ushort*>(&h);
    }
    ushort4 uv = make_ushort4(u[0], u[1], u[2], u[3]);
    ((ushort4*)marr)[i] = uv;
}

// ---------------- fused softmax-aggregation + MessageNorm ----------------
// Gathers bf16 messages; self term read fp32 (MODE 1 applies BN-affine+relu+eps to self).
template <int MODE>
__global__ __launch_bounds__(256) void agg_k(const float* __restrict__ xin,
                                             const float* __restrict__ ta,
                                             const float* __restrict__ tc,
                                             const __hip_bfloat16* __restrict__ marr,
                                             const int* __restrict__ rs,
                                             const int* __restrict__ col,
                                             const float* __restrict__ t,
                                             const float* __restrict__ sc,
                                             int layer, float* __restrict__ outb, int N) {
    int lane = threadIdx.x & 63;
    int wid = threadIdx.x >> 6;
    int n = blockIdx.x * 4 + wid;
    if (n >= N) return;
    float tv = t[layer];
    float sv = sc[layer];

    int beg = rs[n], end = rs[n + 1];
    float den = 0.f, num = 0.f;
    int e = beg;
    for (; e + 3 < end; e += 4) {
        int s0 = col[e], s1 = col[e + 1], s2 = col[e + 2], s3 = col[e + 3];
        float m0 = b2f(marr[s0 * C + lane]);
        float m1 = b2f(marr[s1 * C + lane]);
        float m2 = b2f(marr[s2 * C + lane]);
        float m3 = b2f(marr[s3 * C + lane]);
        float e0 = __expf(m0 * tv);
        float e1 = __expf(m1 * tv);
        float e2 = __expf(m2 * tv);
        float e3 = __expf(m3 * tv);
        den += e0 + e1 + e2 + e3;
        num += m0 * e0 + m1 * e1 + m2 * e2 + m3 * e3;
    }
    for (; e < end; e++) {
        int s0 = col[e];
        float m0 = b2f(marr[s0 * C + lane]);
        float e0 = __expf(m0 * tv);
        den += e0;
        num += m0 * e0;
    }
    float agg = (den > 0.f) ? (num / den) : 0.f;

    float xn;
    if (MODE == 0) {
        xn = xin[n * C + lane];
    } else {
        float v = xin[n * C + lane];
        xn = fmaxf(v * ta[lane] + tc[lane], 0.f) + FEPS;
    }
    float na = wave_sum(agg * agg);
    float nx = wave_sum(xn * xn);
    float inv = 1.0f / fmaxf(sqrtf(na), 1e-12f);
    outb[n * C + lane] = xn + agg * inv * sqrtf(nx) * sv;
}

// ---------------- tiled MLP GEMM: out[N,ND] = act(A[N,KD]) @ W[KD,ND] + bias ----------------
// AFF=1: A element (row,k) -> relu(A*fa[k]+fc[k])  (fused BN+relu of previous stage)
// Also accumulates column sum/sumsq of out into s_sum/s_ssq (for next BN).
template <int KD, int ND, int AFF>
__global__ __launch_bounds__(256) void mlp_k(const float* __restrict__ A,
                                             const float* __restrict__ fa,
                                             const float* __restrict__ fc,
                                             const float* __restrict__ Wg,
                                             const float* __restrict__ bias,
                                             float* __restrict__ outp,
                                             float* __restrict__ s_sum,
                                             float* __restrict__ s_ssq, int N) {
    constexpr int AST = KD + 4;           // padded A stride
    constexpr int NG = ND / 64;           // col groups of 4 per thread
    __shared__ float Ws[KD * ND];
    __shared__ float As[64 * AST];
    __shared__ float faf[AFF ? KD : 1][2];
    __shared__ float st[ND][2];

    int tid = threadIdx.x;
    // stage W (coalesced float4)
    for (int i = tid; i < KD * ND / 4; i += 256)
        ((float4*)Ws)[i] = ((const float4*)Wg)[i];
    if (AFF) {
        for (int i = tid; i < KD; i += 256) { faf[i][0] = fa[i]; faf[i][1] = fc[i]; }
    }
    if (tid < ND) { st[tid][0] = 0.f; st[tid][1] = 0.f; }
    __syncthreads();   // faf/st visible before A-tile staging uses them

    // stage A tile (64 rows), fused affine+relu if AFF
    int base = blockIdx.x * 64;
    for (int e = tid; e < 64 * KD / 4; e += 256) {
        int row = e / (KD / 4);
        int kk = (e % (KD / 4)) * 4;
        float4 v = make_float4(0.f, 0.f, 0.f, 0.f);
        if (base + row < N) v = ((const float4*)A)[(size_t)(base + row) * (KD / 4) + (kk >> 2)];
        if (AFF) {
            v.x = fmaxf(v.x * faf[kk + 0][0] + faf[kk + 0][1], 0.f);
            v.y = fmaxf(v.y * faf[kk + 1][0] + faf[kk + 1][1], 0.f);
            v.z = fmaxf(v.z * faf[kk + 2][0] + faf[kk + 2][1], 0.f);
            v.w = fmaxf(v.w * faf[kk + 3][0] + faf[kk + 3][1], 0.f);
        }
        *(float4*)&As[row * AST + kk] = v;
    }
    __syncthreads();

    int ri = tid >> 4, ci = tid & 15;
    int r0 = ri * 4;
    float acc[4][NG][4];
#pragma unroll
    for (int j = 0; j < 4; j++)
#pragma unroll
        for (int g = 0; g < NG; g++)
#pragma unroll
            for (int c = 0; c < 4; c++) acc[j][g][c] = 0.f;

    for (int k4 = 0; k4 < KD / 4; k4++) {
        float av[4][4];
#pragma unroll
        for (int j = 0; j < 4; j++) {
            float4 t4 = *(const float4*)&As[(r0 + j) * AST + k4 * 4];
            av[j][0] = t4.x; av[j][1] = t4.y; av[j][2] = t4.z; av[j][3] = t4.w;
        }
#pragma unroll
        for (int kk = 0; kk < 4; kk++) {
            int k = k4 * 4 + kk;
#pragma unroll
            for (int g = 0; g < NG; g++) {
                float4 wv = *(const float4*)&Ws[k * ND + g * 64 + ci * 4];
#pragma unroll
                for (int j = 0; j < 4; j++) {
                    acc[j][g][0] += av[j][kk] * wv.x;
                    acc[j][g][1] += av[j][kk] * wv.y;
                    acc[j][g][2] += av[j][kk] * wv.z;
                    acc[j][g][3] += av[j][kk] * wv.w;
                }
            }
        }
    }

    // epilogue: bias, store, column stats
    float bb[NG][4];
#pragma unroll
    for (int g = 0; g < NG; g++) {
        float4 b4 = *(const float4*)&bias[g * 64 + ci * 4];
        bb[g][0] = b4.x; bb[g][1] = b4.y; bb[g][2] = b4.z; bb[g][3] = b4.w;
    }
    float ls[NG][4], lq[NG][4];
#pragma unroll
    for (int g = 0; g < NG; g++)
#pragma unroll
        for (int c = 0; c < 4; c++) { ls[g][c] = 0.f; lq[g][c] = 0.f; }

#pragma unroll
    for (int j = 0; j < 4; j++) {
        int row = base + r0 + j;
        if (row < N) {
#pragma unroll
            for (int g = 0; g < NG; g++) {
                float4 h4;
                h4.x = acc[j][g][0] + bb[g][0];
                h4.y = acc[j][g][1] + bb[g][1];
                h4.z = acc[j][g][2] + bb[g][2];
                h4.w = acc[j][g][3] + bb[g][3];
                *(float4*)&outp[(size_t)row * ND + g * 64 + ci * 4] = h4;
                ls[g][0] += h4.x; lq[g][0] += h4.x * h4.x;
                ls[g][1] += h4.y; lq[g][1] += h4.y * h4.y;
                ls[g][2] += h4.z; lq[g][2] += h4.z * h4.z;
                ls[g][3] += h4.w; lq[g][3] += h4.w * h4.w;
            }
        }
    }
#pragma unroll
    for (int g = 0; g < NG; g++)
#pragma unroll
        for (int c = 0; c < 4; c++) {
            atomicAdd(&st[g * 64 + ci * 4 + c][0], ls[g][c]);
            atomicAdd(&st[g * 64 + ci * 4 + c][1], lq[g][c]);
        }
    __syncthreads();
    if (tid < ND) {
        atomicAdd(&s_sum[tid], st[tid][0]);
        atomicAdd(&s_ssq[tid], st[tid][1]);
    }
}

// ---------------- BN finalize: a = rsig*g ; c = b - mu*rsig*g ----------------
__global__ void bnfin_k(const float* __restrict__ sum, const float* __restrict__ ssq,
                        const float* __restrict__ g, const float* __restrict__ b,
                        float* __restrict__ a, float* __restrict__ cc, int n, float invN) {
    int i = threadIdx.x;
    if (i < n) {
        float mu = sum[i] * invN;
        float var = ssq[i] * invN - mu * mu;
        float rs = rsqrtf(var + BNE);
        float gg = g[i];
        float bb = b[i];
        a[i] = rs * gg;
        cc[i] = bb - mu * rs * gg;
    }
}

// ---------------- final: out = relu(x0 + (y*a2+c2)) + eps ----------------
__global__ void final_k(const float* __restrict__ x0, const float* __restrict__ y,
                        const float* __restrict__ a2, const float* __restrict__ c2,
                        float* __restrict__ outp, int total) {
    int i = blockIdx.x * 256 + threadIdx.x;
    if (i < total) {
        int c = i & 63;
        float v = y[i] * a2[c] + c2[c];
        float r = fmaxf(x0[i] + v, 0.f) + FEPS;
        outp[i] = r;
    }
}

extern "C" void kernel_launch(void* const* d_in, const int* in_sizes, int n_in,
                              void* d_out, int out_size, void* d_ws, size_t ws_size,
                              hipStream_t stream) {
    const float* x0 = (const float*)d_in[0];
    const int* ei = (const int*)d_in[1];
    const float* t = (const float*)d_in[2];
    const float* scale = (const float*)d_in[3];
    const float* W1 = (const float*)d_in[4];
    const float* b1 = (const float*)d_in[5];
    const float* g1 = (const float*)d_in[6];
    const float* be1 = (const float*)d_in[7];
    const float* W2 = (const float*)d_in[8];
    const float* b2 = (const float*)d_in[9];
    const float* bn_g = (const float*)d_in[10];
    const float* bn_b = (const float*)d_in[11];

    const int N = in_sizes[0] / C;
    const int E = in_sizes[1] / 2;
    const int* src = ei;
    const int* dst = ei + E;

    char* ws = (char*)d_ws;
    size_t cur = 0;
    auto alloc = [&](size_t bytes) -> char* {
        char* p = ws + cur;
        cur = (cur + bytes + 255) & ~(size_t)255;
        return p;
    };
    int* counts = (int*)alloc((size_t)N * 4);
    int* fill = (int*)alloc((size_t)N * 4);
    float* stats = (float*)alloc(768 * 4);          // [layer][sum1 128|ssq1 128|sum2 64|ssq2 64]
    size_t zbytes = cur;                            // zero everything above each call
    float* params = (float*)alloc(768 * 4);         // [layer][a1 128|c1 128|a2 64|c2 64]
    int* partials = (int*)alloc(1024 * 4);
    int* row_start = (int*)alloc(((size_t)N + 1) * 4);
    int* col = (int*)alloc((size_t)E * 4);
    ushort* marr = (ushort*)alloc((size_t)N * C * 2);   // bf16 messages
    float* bout = (float*)alloc((size_t)N * C * 4);
    float* bh = (float*)alloc((size_t)N * H * 4);
    float* by = (float*)alloc((size_t)N * C * 4);

    hipMemsetAsync(d_ws, 0, zbytes, stream);

    // CSR build
    int nbE = (E + 255) / 256;
    int nb1 = (N + 255) / 256;
    hist_k<<<nbE, 256, 0, stream>>>(dst, counts, E);
    scan1_k<<<nb1, 256, 0, stream>>>(counts, row_start, partials, N);
    scan2_k<<<1, 1024, 0, stream>>>(partials, nb1);
    int nb3 = (N + 256) / 256;
    scan3_k<<<nb3, 256, 0, stream>>>(row_start, partials, N, E);
    scatter_k<<<nbE, 256, 0, stream>>>(src, dst, row_start, fill, col, E);

    float* sum1_0 = stats + 0;   float* ssq1_0 = stats + 128;
    float* sum2_0 = stats + 256; float* ssq2_0 = stats + 320;
    float* sum1_1 = stats + 384; float* ssq1_1 = stats + 512;
    float* sum2_1 = stats + 640; float* ssq2_1 = stats + 704;
    float* a1_0 = params + 0;   float* c1_0 = params + 128;
    float* a2_0 = params + 256; float* c2_0 = params + 320;
    float* a1_1 = params + 384; float* c1_1 = params + 512;
    float* a2_1 = params + 640; float* c2_1 = params + 704;

    const float invN = 1.0f / (float)N;
    int nbN4 = (N + 3) / 4;
    int nbT = (N + 63) / 64;              // GEMM row tiles
    int nbP = (N * C / 4 + 255) / 256;    // prep (4 elems/thread)

    // ---- layer 0 ----
    prep_k<0><<<nbP, 256, 0, stream>>>(x0, nullptr, nullptr, marr, N * C / 4);
    agg_k<0><<<nbN4, 256, 0, stream>>>(x0, nullptr, nullptr,
                                       (const __hip_bfloat16*)marr, row_start, col,
                                       t, scale, 0, bout, N);
    mlp_k<C, H, 0><<<nbT, 256, 0, stream>>>(bout, nullptr, nullptr, W1, b1, bh, sum1_0, ssq1_0, N);
    bnfin_k<<<1, 128, 0, stream>>>(sum1_0, ssq1_0, g1, be1, a1_0, c1_0, H, invN);
    mlp_k<H, C, 1><<<nbT, 256, 0, stream>>>(bh, a1_0, c1_0, W2, b2, by, sum2_0, ssq2_0, N);
    bnfin_k<<<1, 64, 0, stream>>>(sum2_0, ssq2_0, bn_g, bn_b, a2_0, c2_0, C, invN);

    // ---- layer 1 ----
    prep_k<1><<<nbP, 256, 0, stream>>>(by, a2_0, c2_0, marr, N * C / 4);
    agg_k<1><<<nbN4, 256, 0, stream>>>(by, a2_0, c2_0,
                                       (const __hip_bfloat16*)marr, row_start, col,
                                       t, scale, 1, bout, N);
    mlp_k<C, H, 0><<<nbT, 256, 0, stream>>>(bout, nullptr, nullptr, W1 + C * H, b1 + H, bh, sum1_1, ssq1_1, N);
    bnfin_k<<<1, 128, 0, stream>>>(sum1_1, ssq1_1, g1 + H, be1 + H, a1_1, c1_1, H, invN);
    mlp_k<H, C, 1><<<nbT, 256, 0, stream>>>(bh, a1_1, c1_1, W2 + H * C, b2 + C, by, sum2_1, ssq2_1, N);
    bnfin_k<<<1, 64, 0, stream>>>(sum2_1, ssq2_1, bn_g + C, bn_b + C, a2_1, c2_1, C, invN);

    // ---- residual + relu + eps ----
    final_k<<<(N * C + 255) / 256, 256, 0, stream>>>(x0, by, a2_1, c2_1,
                                                     (float*)d_out, N * C);
}

// Round 6
// 518.732 us; speedup vs baseline: 1.6197x; 1.2156x over previous
//
#include <hip/hip_runtime.h>
#include <hip/hip_bf16.h>

#define C 64
#define H 128
#define FEPS 1e-7f
#define BNE 1e-5f
#define BSH 9
#define BSZ 512   // nodes per bucket

__device__ __forceinline__ float b2f(__hip_bfloat16 v) { return __bfloat162float(v); }

__device__ __forceinline__ float wave_sum(float v) {
#pragma unroll
    for (int m = 32; m > 0; m >>= 1) v += __shfl_xor(v, m, 64);
    return v;
}

// ---------------- CSR build (bucketed, no random global atomics) ----------------
// Bucket = 512 consecutive dst nodes. 1) global bucket histogram via LDS,
// 2) scan, 3) scatter (src,dst) pairs grouped by bucket (L2-packed writes),
// 4) per-bucket: node counts + LDS scan -> row_start, then fine scatter of col
//    into a ~33KB L2-resident window.

__global__ __launch_bounds__(256) void bhist_k(const int* __restrict__ dst,
                                               int* __restrict__ bucket_cnt, int E, int NB) {
    __shared__ int cnt[256];
    int tid = threadIdx.x;
    cnt[tid] = 0;
    __syncthreads();
    int base = blockIdx.x * 4096;
#pragma unroll
    for (int j = 0; j < 16; j++) {
        int e = base + tid + j * 256;
        if (e < E) atomicAdd(&cnt[dst[e] >> BSH], 1);
    }
    __syncthreads();
    if (tid < NB && cnt[tid]) atomicAdd(&bucket_cnt[tid], cnt[tid]);
}

__global__ void bscan_k(const int* __restrict__ bucket_cnt, int* __restrict__ bucket_off,
                        int* __restrict__ bucket_fill, int* __restrict__ row_start,
                        int NB, int N, int E) {
    __shared__ int s[256];
    int tid = threadIdx.x;
    int v = (tid < NB) ? bucket_cnt[tid] : 0;
    s[tid] = v;
    __syncthreads();
    for (int off = 1; off < 256; off <<= 1) {
        int t = 0;
        if (tid >= off) t = s[tid - off];
        __syncthreads();
        s[tid] += t;
        __syncthreads();
    }
    int excl = s[tid] - v;
    if (tid < NB) { bucket_off[tid] = excl; bucket_fill[tid] = excl; }
    if (tid == NB - 1) bucket_off[NB] = s[tid];
    if (tid == 0) row_start[N] = E;
}

__global__ __launch_bounds__(256) void bscat_k(const int* __restrict__ src,
                                               const int* __restrict__ dst,
                                               int* __restrict__ bucket_fill,
                                               int* __restrict__ bsrc, int* __restrict__ bdst,
                                               int E) {
    __shared__ int cnt[256];
    __shared__ int sbase[256];
    int tid = threadIdx.x;
    cnt[tid] = 0;
    __syncthreads();
    int base = blockIdx.x * 4096;
    int dd[16], rk[16];
#pragma unroll
    for (int j = 0; j < 16; j++) {
        int e = base + tid + j * 256;
        dd[j] = -1;
        if (e < E) {
            int d = dst[e];
            dd[j] = d;
            rk[j] = atomicAdd(&cnt[d >> BSH], 1);
        }
    }
    __syncthreads();
    if (cnt[tid]) sbase[tid] = atomicAdd(&bucket_fill[tid], cnt[tid]);
    __syncthreads();
#pragma unroll
    for (int j = 0; j < 16; j++) {
        int e = base + tid + j * 256;
        if (dd[j] >= 0) {
            int b = dd[j] >> BSH;
            int pos = sbase[b] + rk[j];
            bsrc[pos] = src[e];
            bdst[pos] = dd[j];
        }
    }
}

__global__ __launch_bounds__(256) void bfine_k(const int* __restrict__ bucket_off,
                                               const int* __restrict__ bsrc,
                                               const int* __restrict__ bdst,
                                               int* __restrict__ row_start,
                                               int* __restrict__ col, int N) {
    __shared__ int cnt[BSZ];
    __shared__ int off[BSZ];
    __shared__ int fill[BSZ];
    __shared__ int s[256];
    int tid = threadIdx.x;
    int b = blockIdx.x;
    int e0 = bucket_off[b], e1 = bucket_off[b + 1];
    int nbase = b << BSH;
    cnt[tid] = 0; cnt[tid + 256] = 0;
    fill[tid] = 0; fill[tid + 256] = 0;
    __syncthreads();
    for (int e = e0 + tid; e < e1; e += 256) atomicAdd(&cnt[bdst[e] - nbase], 1);
    __syncthreads();
    int a = cnt[2 * tid], bb = cnt[2 * tid + 1];
    s[tid] = a + bb;
    __syncthreads();
    for (int o = 1; o < 256; o <<= 1) {
        int t = 0;
        if (tid >= o) t = s[tid - o];
        __syncthreads();
        s[tid] += t;
        __syncthreads();
    }
    int excl = s[tid] - (a + bb);
    off[2 * tid] = excl;
    off[2 * tid + 1] = excl + a;
    __syncthreads();
    // row_start for this bucket's nodes (coalesced)
    for (int i = tid; i < BSZ; i += 256) {
        int n = nbase + i;
        if (n < N) row_start[n] = e0 + off[i];
    }
    // fine scatter into L2-resident window
    for (int e = e0 + tid; e < e1; e += 256) {
        int d = bdst[e];
        int loc = d - nbase;
        int sv = bsrc[e];
        int r = atomicAdd(&fill[loc], 1);
        col[e0 + off[loc] + r] = sv;
    }
}

// ---------------- message prep: marr = bf16(relu(x)+eps), x possibly BN-affined ----------------
template <int AFF>
__global__ __launch_bounds__(256) void prep_k(const float* __restrict__ in,
                                              const float* __restrict__ fa,
                                              const float* __restrict__ fc,
                                              ushort* __restrict__ marr, int total4) {
    int i = blockIdx.x * 256 + threadIdx.x;
    if (i >= total4) return;
    float4 v = ((const float4*)in)[i];
    int c0 = (i * 4) & 63;
    float vv[4] = {v.x, v.y, v.z, v.w};
    ushort u[4];
#pragma unroll
    for (int j = 0; j < 4; j++) {
        float x = vv[j];
        if (AFF) {
            float xv = fmaxf(x * fa[c0 + j] + fc[c0 + j], 0.f) + FEPS;
            x = xv + FEPS;
        } else {
            x = fmaxf(x, 0.f) + FEPS;
        }
        __hip_bfloat16 h = __float2bfloat16(x);
        u[j] = *reinterpret_cast<ushort*>(&h);
    }
    ushort4 uv = make_ushort4(u[0], u[1], u[2], u[3]);
    ((ushort4*)marr)[i] = uv;
}

// ---------------- fused softmax-aggregation + MessageNorm ----------------
template <int MODE>
__global__ __launch_bounds__(256) void agg_k(const float* __restrict__ xin,
                                             const float* __restrict__ ta,
                                             const float* __restrict__ tc,
                                             const __hip_bfloat16* __restrict__ marr,
                                             const int* __restrict__ rs,
                                             const int* __restrict__ col,
                                             const float* __restrict__ t,
                                             const float* __restrict__ sc,
                                             int layer, float* __restrict__ outb, int N) {
    int lane = threadIdx.x & 63;
    int wid = threadIdx.x >> 6;
    int n = blockIdx.x * 4 + wid;
    if (n >= N) return;
    float tv = t[layer];
    float sv = sc[layer];

    int beg = rs[n], end = rs[n + 1];
    float den = 0.f, num = 0.f;
    int e = beg;
    for (; e + 3 < end; e += 4) {
        int s0 = col[e], s1 = col[e + 1], s2 = col[e + 2], s3 = col[e + 3];
        float m0 = b2f(marr[s0 * C + lane]);
        float m1 = b2f(marr[s1 * C + lane]);
        float m2 = b2f(marr[s2 * C + lane]);
        float m3 = b2f(marr[s3 * C + lane]);
        float e0 = __expf(m0 * tv);
        float e1 = __expf(m1 * tv);
        float e2 = __expf(m2 * tv);
        float e3 = __expf(m3 * tv);
        den += e0 + e1 + e2 + e3;
        num += m0 * e0 + m1 * e1 + m2 * e2 + m3 * e3;
    }
    for (; e < end; e++) {
        int s0 = col[e];
        float m0 = b2f(marr[s0 * C + lane]);
        float e0 = __expf(m0 * tv);
        den += e0;
        num += m0 * e0;
    }
    float agg = (den > 0.f) ? (num / den) : 0.f;

    float xn;
    if (MODE == 0) {
        xn = xin[n * C + lane];
    } else {
        float v = xin[n * C + lane];
        xn = fmaxf(v * ta[lane] + tc[lane], 0.f) + FEPS;
    }
    float na = wave_sum(agg * agg);
    float nx = wave_sum(xn * xn);
    float inv = 1.0f / fmaxf(sqrtf(na), 1e-12f);
    outb[n * C + lane] = xn + agg * inv * sqrtf(nx) * sv;
}

// ---------------- tiled MLP GEMM: out[N,ND] = act(A[N,KD]) @ W[KD,ND] + bias ----------------
template <int KD, int ND, int AFF>
__global__ __launch_bounds__(256) void mlp_k(const float* __restrict__ A,
                                             const float* __restrict__ fa,
                                             const float* __restrict__ fc,
                                             const float* __restrict__ Wg,
                                             const float* __restrict__ bias,
                                             float* __restrict__ outp,
                                             float* __restrict__ s_sum,
                                             float* __restrict__ s_ssq, int N) {
    constexpr int AST = KD + 4;           // padded A stride
    constexpr int NG = ND / 64;           // col groups of 4 per thread
    __shared__ float Ws[KD * ND];
    __shared__ float As[64 * AST];
    __shared__ float faf[AFF ? KD : 1][2];
    __shared__ float st[ND][2];

    int tid = threadIdx.x;
    for (int i = tid; i < KD * ND / 4; i += 256)
        ((float4*)Ws)[i] = ((const float4*)Wg)[i];
    if (AFF) {
        for (int i = tid; i < KD; i += 256) { faf[i][0] = fa[i]; faf[i][1] = fc[i]; }
    }
    if (tid < ND) { st[tid][0] = 0.f; st[tid][1] = 0.f; }
    __syncthreads();   // faf/st visible before A-tile staging uses them

    int base = blockIdx.x * 64;
    for (int e = tid; e < 64 * KD / 4; e += 256) {
        int row = e / (KD / 4);
        int kk = (e % (KD / 4)) * 4;
        float4 v = make_float4(0.f, 0.f, 0.f, 0.f);
        if (base + row < N) v = ((const float4*)A)[(size_t)(base + row) * (KD / 4) + (kk >> 2)];
        if (AFF) {
            v.x = fmaxf(v.x * faf[kk + 0][0] + faf[kk + 0][1], 0.f);
            v.y = fmaxf(v.y * faf[kk + 1][0] + faf[kk + 1][1], 0.f);
            v.z = fmaxf(v.z * faf[kk + 2][0] + faf[kk + 2][1], 0.f);
            v.w = fmaxf(v.w * faf[kk + 3][0] + faf[kk + 3][1], 0.f);
        }
        *(float4*)&As[row * AST + kk] = v;
    }
    __syncthreads();

    int ri = tid >> 4, ci = tid & 15;
    int r0 = ri * 4;
    float acc[4][NG][4];
#pragma unroll
    for (int j = 0; j < 4; j++)
#pragma unroll
        for (int g = 0; g < NG; g++)
#pragma unroll
            for (int c = 0; c < 4; c++) acc[j][g][c] = 0.f;

    for (int k4 = 0; k4 < KD / 4; k4++) {
        float av[4][4];
#pragma unroll
        for (int j = 0; j < 4; j++) {
            float4 t4 = *(const float4*)&As[(r0 + j) * AST + k4 * 4];
            av[j][0] = t4.x; av[j][1] = t4.y; av[j][2] = t4.z; av[j][3] = t4.w;
        }
#pragma unroll
        for (int kk = 0; kk < 4; kk++) {
            int k = k4 * 4 + kk;
#pragma unroll
            for (int g = 0; g < NG; g++) {
                float4 wv = *(const float4*)&Ws[k * ND + g * 64 + ci * 4];
#pragma unroll
                for (int j = 0; j < 4; j++) {
                    acc[j][g][0] += av[j][kk] * wv.x;
                    acc[j][g][1] += av[j][kk] * wv.y;
                    acc[j][g][2] += av[j][kk] * wv.z;
                    acc[j][g][3] += av[j][kk] * wv.w;
                }
            }
        }
    }

    float bb[NG][4];
#pragma unroll
    for (int g = 0; g < NG; g++) {
        float4 b4 = *(const float4*)&bias[g * 64 + ci * 4];
        bb[g][0] = b4.x; bb[g][1] = b4.y; bb[g][2] = b4.z; bb[g][3] = b4.w;
    }
    float ls[NG][4], lq[NG][4];
#pragma unroll
    for (int g = 0; g < NG; g++)
#pragma unroll
        for (int c = 0; c < 4; c++) { ls[g][c] = 0.f; lq[g][c] = 0.f; }

#pragma unroll
    for (int j = 0; j < 4; j++) {
        int row = base + r0 + j;
        if (row < N) {
#pragma unroll
            for (int g = 0; g < NG; g++) {
                float4 h4;
                h4.x = acc[j][g][0] + bb[g][0];
                h4.y = acc[j][g][1] + bb[g][1];
                h4.z = acc[j][g][2] + bb[g][2];
                h4.w = acc[j][g][3] + bb[g][3];
                *(float4*)&outp[(size_t)row * ND + g * 64 + ci * 4] = h4;
                ls[g][0] += h4.x; lq[g][0] += h4.x * h4.x;
                ls[g][1] += h4.y; lq[g][1] += h4.y * h4.y;
                ls[g][2] += h4.z; lq[g][2] += h4.z * h4.z;
                ls[g][3] += h4.w; lq[g][3] += h4.w * h4.w;
            }
        }
    }
#pragma unroll
    for (int g = 0; g < NG; g++)
#pragma unroll
        for (int c = 0; c < 4; c++) {
            atomicAdd(&st[g * 64 + ci * 4 + c][0], ls[g][c]);
            atomicAdd(&st[g * 64 + ci * 4 + c][1], lq[g][c]);
        }
    __syncthreads();
    if (tid < ND) {
        atomicAdd(&s_sum[tid], st[tid][0]);
        atomicAdd(&s_ssq[tid], st[tid][1]);
    }
}

// ---------------- BN finalize ----------------
__global__ void bnfin_k(const float* __restrict__ sum, const float* __restrict__ ssq,
                        const float* __restrict__ g, const float* __restrict__ b,
                        float* __restrict__ a, float* __restrict__ cc, int n, float invN) {
    int i = threadIdx.x;
    if (i < n) {
        float mu = sum[i] * invN;
        float var = ssq[i] * invN - mu * mu;
        float rs = rsqrtf(var + BNE);
        float gg = g[i];
        float bb = b[i];
        a[i] = rs * gg;
        cc[i] = bb - mu * rs * gg;
    }
}

// ---------------- final: out = relu(x0 + (y*a2+c2)) + eps ----------------
__global__ void final_k(const float* __restrict__ x0, const float* __restrict__ y,
                        const float* __restrict__ a2, const float* __restrict__ c2,
                        float* __restrict__ outp, int total) {
    int i = blockIdx.x * 256 + threadIdx.x;
    if (i < total) {
        int c = i & 63;
        float v = y[i] * a2[c] + c2[c];
        float r = fmaxf(x0[i] + v, 0.f) + FEPS;
        outp[i] = r;
    }
}

extern "C" void kernel_launch(void* const* d_in, const int* in_sizes, int n_in,
                              void* d_out, int out_size, void* d_ws, size_t ws_size,
                              hipStream_t stream) {
    const float* x0 = (const float*)d_in[0];
    const int* ei = (const int*)d_in[1];
    const float* t = (const float*)d_in[2];
    const float* scale = (const float*)d_in[3];
    const float* W1 = (const float*)d_in[4];
    const float* b1 = (const float*)d_in[5];
    const float* g1 = (const float*)d_in[6];
    const float* be1 = (const float*)d_in[7];
    const float* W2 = (const float*)d_in[8];
    const float* b2 = (const float*)d_in[9];
    const float* bn_g = (const float*)d_in[10];
    const float* bn_b = (const float*)d_in[11];

    const int N = in_sizes[0] / C;
    const int E = in_sizes[1] / 2;
    const int* src = ei;
    const int* dst = ei + E;
    const int NB = (N + BSZ - 1) >> BSH;   // 196 buckets (<=256 required)

    char* ws = (char*)d_ws;
    size_t cur = 0;
    auto alloc = [&](size_t bytes) -> char* {
        char* p = ws + cur;
        cur = (cur + bytes + 255) & ~(size_t)255;
        return p;
    };
    int* bucket_cnt = (int*)alloc(256 * 4);
    float* stats = (float*)alloc(768 * 4);          // [layer][sum1 128|ssq1 128|sum2 64|ssq2 64]
    size_t zbytes = cur;                            // zero only atomic targets
    float* params = (float*)alloc(768 * 4);         // [layer][a1 128|c1 128|a2 64|c2 64]
    int* bucket_off = (int*)alloc(257 * 4);
    int* bucket_fill = (int*)alloc(256 * 4);
    int* row_start = (int*)alloc(((size_t)N + 1) * 4);
    int* col = (int*)alloc((size_t)E * 4);
    ushort* marr = (ushort*)alloc((size_t)N * C * 2);   // bf16 messages
    float* bout = (float*)alloc((size_t)N * C * 4);
    float* bh = (float*)alloc((size_t)N * H * 4);
    float* by = (float*)alloc((size_t)N * C * 4);
    // bsrc/bdst alias bh: CSR build finishes before first mlp_k uses bh
    int* bsrc = (int*)bh;
    int* bdst = bsrc + E;

    hipMemsetAsync(d_ws, 0, zbytes, stream);

    // CSR build (bucketed)
    int nbE16 = (E + 4095) / 4096;
    bhist_k<<<nbE16, 256, 0, stream>>>(dst, bucket_cnt, E, NB);
    bscan_k<<<1, 256, 0, stream>>>(bucket_cnt, bucket_off, bucket_fill, row_start, NB, N, E);
    bscat_k<<<nbE16, 256, 0, stream>>>(src, dst, bucket_fill, bsrc, bdst, E);
    bfine_k<<<NB, 256, 0, stream>>>(bucket_off, bsrc, bdst, row_start, col, N);

    float* sum1_0 = stats + 0;   float* ssq1_0 = stats + 128;
    float* sum2_0 = stats + 256; float* ssq2_0 = stats + 320;
    float* sum1_1 = stats + 384; float* ssq1_1 = stats + 512;
    float* sum2_1 = stats + 640; float* ssq2_1 = stats + 704;
    float* a1_0 = params + 0;   float* c1_0 = params + 128;
    float* a2_0 = params + 256; float* c2_0 = params + 320;
    float* a1_1 = params + 384; float* c1_1 = params + 512;
    float* a2_1 = params + 640; float* c2_1 = params + 704;

    const float invN = 1.0f / (float)N;
    int nbN4 = (N + 3) / 4;
    int nbT = (N + 63) / 64;              // GEMM row tiles
    int nbP = (N * C / 4 + 255) / 256;    // prep (4 elems/thread)

    // ---- layer 0 ----
    prep_k<0><<<nbP, 256, 0, stream>>>(x0, nullptr, nullptr, marr, N * C / 4);
    agg_k<0><<<nbN4, 256, 0, stream>>>(x0, nullptr, nullptr,
                                       (const __hip_bfloat16*)marr, row_start, col,
                                       t, scale, 0, bout, N);
    mlp_k<C, H, 0><<<nbT, 256, 0, stream>>>(bout, nullptr, nullptr, W1, b1, bh, sum1_0, ssq1_0, N);
    bnfin_k<<<1, 128, 0, stream>>>(sum1_0, ssq1_0, g1, be1, a1_0, c1_0, H, invN);
    mlp_k<H, C, 1><<<nbT, 256, 0, stream>>>(bh, a1_0, c1_0, W2, b2, by, sum2_0, ssq2_0, N);
    bnfin_k<<<1, 64, 0, stream>>>(sum2_0, ssq2_0, bn_g, bn_b, a2_0, c2_0, C, invN);

    // ---- layer 1 ----
    prep_k<1><<<nbP, 256, 0, stream>>>(by, a2_0, c2_0, marr, N * C / 4);
    agg_k<1><<<nbN4, 256, 0, stream>>>(by, a2_0, c2_0,
                                       (const __hip_bfloat16*)marr, row_start, col,
                                       t, scale, 1, bout, N);
    mlp_k<C, H, 0><<<nbT, 256, 0, stream>>>(bout, nullptr, nullptr, W1 + C * H, b1 + H, bh, sum1_1, ssq1_1, N);
    bnfin_k<<<1, 128, 0, stream>>>(sum1_1, ssq1_1, g1 + H, be1 + H, a1_1, c1_1, H, invN);
    mlp_k<H, C, 1><<<nbT, 256, 0, stream>>>(bh, a1_1, c1_1, W2 + H * C, b2 + C, by, sum2_1, ssq2_1, N);
    bnfin_k<<<1, 64, 0, stream>>>(sum2_1, ssq2_1, bn_g + C, bn_b + C, a2_1, c2_1, C, invN);

    // ---- residual + relu + eps ----
    final_k<<<(N * C + 255) / 256, 256, 0, stream>>>(x0, by, a2_1, c2_1,
                                                     (float*)d_out, N * C);
}

// Round 7
// 511.827 us; speedup vs baseline: 1.6415x; 1.0135x over previous
//
#include <hip/hip_runtime.h>
#include <hip/hip_bf16.h>

#define C 64
#define H 128
#define FEPS 1e-7f
#define BNE 1e-5f
#define BSH 9
#define BSZ 512   // nodes per bucket

__device__ __forceinline__ float b2f(__hip_bfloat16 v) { return __bfloat162float(v); }

__device__ __forceinline__ float wave_sum(float v) {
#pragma unroll
    for (int m = 32; m > 0; m >>= 1) v += __shfl_xor(v, m, 64);
    return v;
}

// ---------------- CSR build (bucketed, no random global atomics) ----------------
__global__ __launch_bounds__(256) void bhist_k(const int* __restrict__ dst,
                                               int* __restrict__ bucket_cnt, int E, int NB) {
    __shared__ int cnt[256];
    int tid = threadIdx.x;
    cnt[tid] = 0;
    __syncthreads();
    int base = blockIdx.x * 4096;
#pragma unroll
    for (int j = 0; j < 16; j++) {
        int e = base + tid + j * 256;
        if (e < E) atomicAdd(&cnt[dst[e] >> BSH], 1);
    }
    __syncthreads();
    if (tid < NB && cnt[tid]) atomicAdd(&bucket_cnt[tid], cnt[tid]);
}

__global__ void bscan_k(const int* __restrict__ bucket_cnt, int* __restrict__ bucket_off,
                        int* __restrict__ bucket_fill, int* __restrict__ row_start,
                        int NB, int N, int E) {
    __shared__ int s[256];
    int tid = threadIdx.x;
    int v = (tid < NB) ? bucket_cnt[tid] : 0;
    s[tid] = v;
    __syncthreads();
    for (int off = 1; off < 256; off <<= 1) {
        int t = 0;
        if (tid >= off) t = s[tid - off];
        __syncthreads();
        s[tid] += t;
        __syncthreads();
    }
    int excl = s[tid] - v;
    if (tid < NB) { bucket_off[tid] = excl; bucket_fill[tid] = excl; }
    if (tid == NB - 1) bucket_off[NB] = s[tid];
    if (tid == 0) row_start[N] = E;
}

__global__ __launch_bounds__(256) void bscat_k(const int* __restrict__ src,
                                               const int* __restrict__ dst,
                                               int* __restrict__ bucket_fill,
                                               int* __restrict__ bsrc, int* __restrict__ bdst,
                                               int E) {
    __shared__ int cnt[256];
    __shared__ int sbase[256];
    int tid = threadIdx.x;
    cnt[tid] = 0;
    __syncthreads();
    int base = blockIdx.x * 4096;
    int dd[16], rk[16];
#pragma unroll
    for (int j = 0; j < 16; j++) {
        int e = base + tid + j * 256;
        dd[j] = -1;
        if (e < E) {
            int d = dst[e];
            dd[j] = d;
            rk[j] = atomicAdd(&cnt[d >> BSH], 1);
        }
    }
    __syncthreads();
    if (cnt[tid]) sbase[tid] = atomicAdd(&bucket_fill[tid], cnt[tid]);
    __syncthreads();
#pragma unroll
    for (int j = 0; j < 16; j++) {
        int e = base + tid + j * 256;
        if (dd[j] >= 0) {
            int b = dd[j] >> BSH;
            int pos = sbase[b] + rk[j];
            bsrc[pos] = src[e];
            bdst[pos] = dd[j];
        }
    }
}

__global__ __launch_bounds__(256) void bfine_k(const int* __restrict__ bucket_off,
                                               const int* __restrict__ bsrc,
                                               const int* __restrict__ bdst,
                                               int* __restrict__ row_start,
                                               int* __restrict__ col, int N) {
    __shared__ int cnt[BSZ];
    __shared__ int off[BSZ];
    __shared__ int fill[BSZ];
    __shared__ int s[256];
    int tid = threadIdx.x;
    int b = blockIdx.x;
    int e0 = bucket_off[b], e1 = bucket_off[b + 1];
    int nbase = b << BSH;
    cnt[tid] = 0; cnt[tid + 256] = 0;
    fill[tid] = 0; fill[tid + 256] = 0;
    __syncthreads();
    for (int e = e0 + tid; e < e1; e += 256) atomicAdd(&cnt[bdst[e] - nbase], 1);
    __syncthreads();
    int a = cnt[2 * tid], bb = cnt[2 * tid + 1];
    s[tid] = a + bb;
    __syncthreads();
    for (int o = 1; o < 256; o <<= 1) {
        int t = 0;
        if (tid >= o) t = s[tid - o];
        __syncthreads();
        s[tid] += t;
        __syncthreads();
    }
    int excl = s[tid] - (a + bb);
    off[2 * tid] = excl;
    off[2 * tid + 1] = excl + a;
    __syncthreads();
    for (int i = tid; i < BSZ; i += 256) {
        int n = nbase + i;
        if (n < N) row_start[n] = e0 + off[i];
    }
    for (int e = e0 + tid; e < e1; e += 256) {
        int d = bdst[e];
        int loc = d - nbase;
        int sv = bsrc[e];
        int r = atomicAdd(&fill[loc], 1);
        col[e0 + off[loc] + r] = sv;
    }
}

// ---------------- message prep: marr = bf16(relu(x)+eps), x possibly BN-affined ----------------
template <int AFF>
__global__ __launch_bounds__(256) void prep_k(const float* __restrict__ in,
                                              const float* __restrict__ fa,
                                              const float* __restrict__ fc,
                                              ushort* __restrict__ marr, int total4) {
    int i = blockIdx.x * 256 + threadIdx.x;
    if (i >= total4) return;
    float4 v = ((const float4*)in)[i];
    int c0 = (i * 4) & 63;
    float vv[4] = {v.x, v.y, v.z, v.w};
    ushort u[4];
#pragma unroll
    for (int j = 0; j < 4; j++) {
        float x = vv[j];
        if (AFF) {
            float xv = fmaxf(x * fa[c0 + j] + fc[c0 + j], 0.f) + FEPS;
            x = xv + FEPS;
        } else {
            x = fmaxf(x, 0.f) + FEPS;
        }
        __hip_bfloat16 h = __float2bfloat16(x);
        u[j] = *reinterpret_cast<ushort*>(&h);
    }
    ushort4 uv = make_ushort4(u[0], u[1], u[2], u[3]);
    ((ushort4*)marr)[i] = uv;
}

// ---------------- fused softmax-aggregation + MessageNorm ----------------
// 2-channel-packed, 2-edge-parallel: lane = (half, sl); lane owns channels {2sl, 2sl+1}
// (one dword of the bf16 message row); halves process different edges in parallel.
template <int MODE>
__global__ __launch_bounds__(256) void agg_k(const float* __restrict__ xin,
                                             const float* __restrict__ ta,
                                             const float* __restrict__ tc,
                                             const unsigned int* __restrict__ marr32,
                                             const int* __restrict__ rs,
                                             const int* __restrict__ col,
                                             const float* __restrict__ t,
                                             const float* __restrict__ sc,
                                             int layer, float* __restrict__ outb, int N) {
    int lane = threadIdx.x & 63;
    int wid = threadIdx.x >> 6;
    int n = blockIdx.x * 4 + wid;
    if (n >= N) return;
    int half = lane >> 5;
    int sl = lane & 31;
    float tv = t[layer];
    float sv = sc[layer];

    int beg = rs[n], end = rs[n + 1];
    float den0 = 0.f, num0 = 0.f, den1 = 0.f, num1 = 0.f;
    int e = beg;

    auto acc_edge = [&](unsigned int d) {
        float m0 = __uint_as_float(d << 16);
        float m1 = __uint_as_float(d & 0xffff0000u);
        float e0 = __expf(m0 * tv);
        float e1 = __expf(m1 * tv);
        den0 += e0; num0 += m0 * e0;
        den1 += e1; num1 += m1 * e1;
    };

    for (; e + 4 <= end; e += 4) {
        int cA = col[e + half];
        int cB = col[e + 2 + half];
        unsigned int dA = marr32[cA * 32 + sl];
        unsigned int dB = marr32[cB * 32 + sl];
        acc_edge(dA);
        acc_edge(dB);
    }
    for (; e + 2 <= end; e += 2) {
        int cA = col[e + half];
        unsigned int dA = marr32[cA * 32 + sl];
        acc_edge(dA);
    }
    if (e < end && half == 0) {
        int cA = col[e];
        unsigned int dA = marr32[cA * 32 + sl];
        acc_edge(dA);
    }

    // combine the two edge-halves (after this both halves hold identical sums)
    den0 += __shfl_xor(den0, 32, 64); num0 += __shfl_xor(num0, 32, 64);
    den1 += __shfl_xor(den1, 32, 64); num1 += __shfl_xor(num1, 32, 64);

    float agg0 = (den0 > 0.f) ? (num0 / den0) : 0.f;
    float agg1 = (den1 > 0.f) ? (num1 / den1) : 0.f;

    float2 xv = ((const float2*)xin)[(size_t)n * 32 + sl];
    float xn0, xn1;
    if (MODE == 0) {
        xn0 = xv.x; xn1 = xv.y;
    } else {
        float2 av = ((const float2*)ta)[sl];
        float2 cv = ((const float2*)tc)[sl];
        xn0 = fmaxf(xv.x * av.x + cv.x, 0.f) + FEPS;
        xn1 = fmaxf(xv.y * av.y + cv.y, 0.f) + FEPS;
    }
    // each channel appears in both halves -> wave_sum double-counts -> *0.5
    float na = wave_sum(agg0 * agg0 + agg1 * agg1) * 0.5f;
    float nx = wave_sum(xn0 * xn0 + xn1 * xn1) * 0.5f;
    float s = (1.0f / fmaxf(sqrtf(na), 1e-12f)) * sqrtf(nx) * sv;
    if (half == 0) {
        float2 o;
        o.x = xn0 + agg0 * s;
        o.y = xn1 + agg1 * s;
        ((float2*)outb)[(size_t)n * 32 + sl] = o;
    }
}

// ---------------- tiled MLP GEMM: out[N,ND] = act(A[N,KD]) @ W[KD,ND] + bias ----------------
template <int KD, int ND, int AFF>
__global__ __launch_bounds__(256) void mlp_k(const float* __restrict__ A,
                                             const float* __restrict__ fa,
                                             const float* __restrict__ fc,
                                             const float* __restrict__ Wg,
                                             const float* __restrict__ bias,
                                             float* __restrict__ outp,
                                             float* __restrict__ s_sum,
                                             float* __restrict__ s_ssq, int N) {
    constexpr int AST = KD + 4;           // padded A stride
    constexpr int NG = ND / 64;           // col groups of 4 per thread
    __shared__ float Ws[KD * ND];
    __shared__ float As[64 * AST];
    __shared__ float faf[AFF ? KD : 1][2];
    __shared__ float st[ND][2];

    int tid = threadIdx.x;
    for (int i = tid; i < KD * ND / 4; i += 256)
        ((float4*)Ws)[i] = ((const float4*)Wg)[i];
    if (AFF) {
        for (int i = tid; i < KD; i += 256) { faf[i][0] = fa[i]; faf[i][1] = fc[i]; }
    }
    if (tid < ND) { st[tid][0] = 0.f; st[tid][1] = 0.f; }
    __syncthreads();   // faf/st visible before A-tile staging uses them

    int base = blockIdx.x * 64;
    for (int e = tid; e < 64 * KD / 4; e += 256) {
        int row = e / (KD / 4);
        int kk = (e % (KD / 4)) * 4;
        float4 v = make_float4(0.f, 0.f, 0.f, 0.f);
        if (base + row < N) v = ((const float4*)A)[(size_t)(base + row) * (KD / 4) + (kk >> 2)];
        if (AFF) {
            v.x = fmaxf(v.x * faf[kk + 0][0] + faf[kk + 0][1], 0.f);
            v.y = fmaxf(v.y * faf[kk + 1][0] + faf[kk + 1][1], 0.f);
            v.z = fmaxf(v.z * faf[kk + 2][0] + faf[kk + 2][1], 0.f);
            v.w = fmaxf(v.w * faf[kk + 3][0] + faf[kk + 3][1], 0.f);
        }
        *(float4*)&As[row * AST + kk] = v;
    }
    __syncthreads();

    int ri = tid >> 4, ci = tid & 15;
    int r0 = ri * 4;
    float acc[4][NG][4];
#pragma unroll
    for (int j = 0; j < 4; j++)
#pragma unroll
        for (int g = 0; g < NG; g++)
#pragma unroll
            for (int c = 0; c < 4; c++) acc[j][g][c] = 0.f;

    for (int k4 = 0; k4 < KD / 4; k4++) {
        float av[4][4];
#pragma unroll
        for (int j = 0; j < 4; j++) {
            float4 t4 = *(const float4*)&As[(r0 + j) * AST + k4 * 4];
            av[j][0] = t4.x; av[j][1] = t4.y; av[j][2] = t4.z; av[j][3] = t4.w;
        }
#pragma unroll
        for (int kk = 0; kk < 4; kk++) {
            int k = k4 * 4 + kk;
#pragma unroll
            for (int g = 0; g < NG; g++) {
                float4 wv = *(const float4*)&Ws[k * ND + g * 64 + ci * 4];
#pragma unroll
                for (int j = 0; j < 4; j++) {
                    acc[j][g][0] += av[j][kk] * wv.x;
                    acc[j][g][1] += av[j][kk] * wv.y;
                    acc[j][g][2] += av[j][kk] * wv.z;
                    acc[j][g][3] += av[j][kk] * wv.w;
                }
            }
        }
    }

    float bb[NG][4];
#pragma unroll
    for (int g = 0; g < NG; g++) {
        float4 b4 = *(const float4*)&bias[g * 64 + ci * 4];
        bb[g][0] = b4.x; bb[g][1] = b4.y; bb[g][2] = b4.z; bb[g][3] = b4.w;
    }
    float ls[NG][4], lq[NG][4];
#pragma unroll
    for (int g = 0; g < NG; g++)
#pragma unroll
        for (int c = 0; c < 4; c++) { ls[g][c] = 0.f; lq[g][c] = 0.f; }

#pragma unroll
    for (int j = 0; j < 4; j++) {
        int row = base + r0 + j;
        if (row < N) {
#pragma unroll
            for (int g = 0; g < NG; g++) {
                float4 h4;
                h4.x = acc[j][g][0] + bb[g][0];
                h4.y = acc[j][g][1] + bb[g][1];
                h4.z = acc[j][g][2] + bb[g][2];
                h4.w = acc[j][g][3] + bb[g][3];
                *(float4*)&outp[(size_t)row * ND + g * 64 + ci * 4] = h4;
                ls[g][0] += h4.x; lq[g][0] += h4.x * h4.x;
                ls[g][1] += h4.y; lq[g][1] += h4.y * h4.y;
                ls[g][2] += h4.z; lq[g][2] += h4.z * h4.z;
                ls[g][3] += h4.w; lq[g][3] += h4.w * h4.w;
            }
        }
    }
#pragma unroll
    for (int g = 0; g < NG; g++)
#pragma unroll
        for (int c = 0; c < 4; c++) {
            atomicAdd(&st[g * 64 + ci * 4 + c][0], ls[g][c]);
            atomicAdd(&st[g * 64 + ci * 4 + c][1], lq[g][c]);
        }
    __syncthreads();
    if (tid < ND) {
        atomicAdd(&s_sum[tid], st[tid][0]);
        atomicAdd(&s_ssq[tid], st[tid][1]);
    }
}

// ---------------- BN finalize ----------------
__global__ void bnfin_k(const float* __restrict__ sum, const float* __restrict__ ssq,
                        const float* __restrict__ g, const float* __restrict__ b,
                        float* __restrict__ a, float* __restrict__ cc, int n, float invN) {
    int i = threadIdx.x;
    if (i < n) {
        float mu = sum[i] * invN;
        float var = ssq[i] * invN - mu * mu;
        float rs = rsqrtf(var + BNE);
        float gg = g[i];
        float bb = b[i];
        a[i] = rs * gg;
        cc[i] = bb - mu * rs * gg;
    }
}

// ---------------- final: out = relu(x0 + (y*a2+c2)) + eps (float4) ----------------
__global__ void final_k(const float4* __restrict__ x0, const float4* __restrict__ y,
                        const float* __restrict__ a2, const float* __restrict__ c2,
                        float4* __restrict__ outp, int total4) {
    int i = blockIdx.x * 256 + threadIdx.x;
    if (i >= total4) return;
    int c0 = (i * 4) & 63;
    float4 yv = y[i], xv = x0[i];
    float4 o;
    o.x = fmaxf(xv.x + yv.x * a2[c0 + 0] + c2[c0 + 0], 0.f) + FEPS;
    o.y = fmaxf(xv.y + yv.y * a2[c0 + 1] + c2[c0 + 1], 0.f) + FEPS;
    o.z = fmaxf(xv.z + yv.z * a2[c0 + 2] + c2[c0 + 2], 0.f) + FEPS;
    o.w = fmaxf(xv.w + yv.w * a2[c0 + 3] + c2[c0 + 3], 0.f) + FEPS;
    outp[i] = o;
}

extern "C" void kernel_launch(void* const* d_in, const int* in_sizes, int n_in,
                              void* d_out, int out_size, void* d_ws, size_t ws_size,
                              hipStream_t stream) {
    const float* x0 = (const float*)d_in[0];
    const int* ei = (const int*)d_in[1];
    const float* t = (const float*)d_in[2];
    const float* scale = (const float*)d_in[3];
    const float* W1 = (const float*)d_in[4];
    const float* b1 = (const float*)d_in[5];
    const float* g1 = (const float*)d_in[6];
    const float* be1 = (const float*)d_in[7];
    const float* W2 = (const float*)d_in[8];
    const float* b2 = (const float*)d_in[9];
    const float* bn_g = (const float*)d_in[10];
    const float* bn_b = (const float*)d_in[11];

    const int N = in_sizes[0] / C;
    const int E = in_sizes[1] / 2;
    const int* src = ei;
    const int* dst = ei + E;
    const int NB = (N + BSZ - 1) >> BSH;   // buckets (<=256 required)

    char* ws = (char*)d_ws;
    size_t cur = 0;
    auto alloc = [&](size_t bytes) -> char* {
        char* p = ws + cur;
        cur = (cur + bytes + 255) & ~(size_t)255;
        return p;
    };
    int* bucket_cnt = (int*)alloc(256 * 4);
    float* stats = (float*)alloc(768 * 4);          // [layer][sum1 128|ssq1 128|sum2 64|ssq2 64]
    size_t zbytes = cur;                            // zero only atomic targets
    float* params = (float*)alloc(768 * 4);         // [layer][a1 128|c1 128|a2 64|c2 64]
    int* bucket_off = (int*)alloc(257 * 4);
    int* bucket_fill = (int*)alloc(256 * 4);
    int* row_start = (int*)alloc(((size_t)N + 1) * 4);
    int* col = (int*)alloc((size_t)E * 4);
    ushort* marr = (ushort*)alloc((size_t)N * C * 2);   // bf16 messages
    float* bout = (float*)alloc((size_t)N * C * 4);
    float* bh = (float*)alloc((size_t)N * H * 4);
    float* by = (float*)alloc((size_t)N * C * 4);
    // bsrc/bdst alias bh: CSR build finishes before first mlp_k uses bh
    int* bsrc = (int*)bh;
    int* bdst = bsrc + E;

    hipMemsetAsync(d_ws, 0, zbytes, stream);

    // CSR build (bucketed)
    int nbE16 = (E + 4095) / 4096;
    bhist_k<<<nbE16, 256, 0, stream>>>(dst, bucket_cnt, E, NB);
    bscan_k<<<1, 256, 0, stream>>>(bucket_cnt, bucket_off, bucket_fill, row_start, NB, N, E);
    bscat_k<<<nbE16, 256, 0, stream>>>(src, dst, bucket_fill, bsrc, bdst, E);
    bfine_k<<<NB, 256, 0, stream>>>(bucket_off, bsrc, bdst, row_start, col, N);

    float* sum1_0 = stats + 0;   float* ssq1_0 = stats + 128;
    float* sum2_0 = stats + 256; float* ssq2_0 = stats + 320;
    float* sum1_1 = stats + 384; float* ssq1_1 = stats + 512;
    float* sum2_1 = stats + 640; float* ssq2_1 = stats + 704;
    float* a1_0 = params + 0;   float* c1_0 = params + 128;
    float* a2_0 = params + 256; float* c2_0 = params + 320;
    float* a1_1 = params + 384; float* c1_1 = params + 512;
    float* a2_1 = params + 640; float* c2_1 = params + 704;

    const float invN = 1.0f / (float)N;
    int nbN4 = (N + 3) / 4;
    int nbT = (N + 63) / 64;              // GEMM row tiles
    int nbP = (N * C / 4 + 255) / 256;    // prep/final (4 elems/thread)

    // ---- layer 0 ----
    prep_k<0><<<nbP, 256, 0, stream>>>(x0, nullptr, nullptr, marr, N * C / 4);
    agg_k<0><<<nbN4, 256, 0, stream>>>(x0, nullptr, nullptr,
                                       (const unsigned int*)marr, row_start, col,
                                       t, scale, 0, bout, N);
    mlp_k<C, H, 0><<<nbT, 256, 0, stream>>>(bout, nullptr, nullptr, W1, b1, bh, sum1_0, ssq1_0, N);
    bnfin_k<<<1, 128, 0, stream>>>(sum1_0, ssq1_0, g1, be1, a1_0, c1_0, H, invN);
    mlp_k<H, C, 1><<<nbT, 256, 0, stream>>>(bh, a1_0, c1_0, W2, b2, by, sum2_0, ssq2_0, N);
    bnfin_k<<<1, 64, 0, stream>>>(sum2_0, ssq2_0, bn_g, bn_b, a2_0, c2_0, C, invN);

    // ---- layer 1 ----
    prep_k<1><<<nbP, 256, 0, stream>>>(by, a2_0, c2_0, marr, N * C / 4);
    agg_k<1><<<nbN4, 256, 0, stream>>>(by, a2_0, c2_0,
                                       (const unsigned int*)marr, row_start, col,
                                       t, scale, 1, bout, N);
    mlp_k<C, H, 0><<<nbT, 256, 0, stream>>>(bout, nullptr, nullptr, W1 + C * H, b1 + H, bh, sum1_1, ssq1_1, N);
    bnfin_k<<<1, 128, 0, stream>>>(sum1_1, ssq1_1, g1 + H, be1 + H, a1_1, c1_1, H, invN);
    mlp_k<H, C, 1><<<nbT, 256, 0, stream>>>(bh, a1_1, c1_1, W2 + H * C, b2 + C, by, sum2_1, ssq2_1, N);
    bnfin_k<<<1, 64, 0, stream>>>(sum2_1, ssq2_1, bn_g + C, bn_b + C, a2_1, c2_1, C, invN);

    // ---- residual + relu + eps ----
    final_k<<<nbP, 256, 0, stream>>>((const float4*)x0, (const float4*)by, a2_1, c2_1,
                                     (float4*)d_out, N * C / 4);
}

// Round 8
// 489.738 us; speedup vs baseline: 1.7156x; 1.0451x over previous
//
#include <hip/hip_runtime.h>
#include <hip/hip_bf16.h>

#define C 64
#define H 128
#define FEPS 1e-7f
#define BNE 1e-5f
#define BSH 9
#define BSZ 512   // nodes per bucket

__device__ __forceinline__ float b2f(__hip_bfloat16 v) { return __bfloat162float(v); }

__device__ __forceinline__ float wave_sum(float v) {
#pragma unroll
    for (int m = 32; m > 0; m >>= 1) v += __shfl_xor(v, m, 64);
    return v;
}

// ---------------- CSR build (bucketed, no random global atomics) ----------------
__global__ __launch_bounds__(256) void bhist_k(const int* __restrict__ dst,
                                               int* __restrict__ bucket_cnt, int E, int NB) {
    __shared__ int cnt[256];
    int tid = threadIdx.x;
    cnt[tid] = 0;
    __syncthreads();
    int base = blockIdx.x * 4096;
#pragma unroll
    for (int j = 0; j < 16; j++) {
        int e = base + tid + j * 256;
        if (e < E) atomicAdd(&cnt[dst[e] >> BSH], 1);
    }
    __syncthreads();
    if (tid < NB && cnt[tid]) atomicAdd(&bucket_cnt[tid], cnt[tid]);
}

__global__ void bscan_k(const int* __restrict__ bucket_cnt, int* __restrict__ bucket_off,
                        int* __restrict__ bucket_fill, int* __restrict__ row_start,
                        int NB, int N, int E) {
    __shared__ int s[256];
    int tid = threadIdx.x;
    int v = (tid < NB) ? bucket_cnt[tid] : 0;
    s[tid] = v;
    __syncthreads();
    for (int off = 1; off < 256; off <<= 1) {
        int t = 0;
        if (tid >= off) t = s[tid - off];
        __syncthreads();
        s[tid] += t;
        __syncthreads();
    }
    int excl = s[tid] - v;
    if (tid < NB) { bucket_off[tid] = excl; bucket_fill[tid] = excl; }
    if (tid == NB - 1) bucket_off[NB] = s[tid];
    if (tid == 0) row_start[N] = E;
}

__global__ __launch_bounds__(256) void bscat_k(const int* __restrict__ src,
                                               const int* __restrict__ dst,
                                               int* __restrict__ bucket_fill,
                                               int* __restrict__ bsrc, int* __restrict__ bdst,
                                               int E) {
    __shared__ int cnt[256];
    __shared__ int sbase[256];
    int tid = threadIdx.x;
    cnt[tid] = 0;
    __syncthreads();
    int base = blockIdx.x * 4096;
    int dd[16], rk[16];
#pragma unroll
    for (int j = 0; j < 16; j++) {
        int e = base + tid + j * 256;
        dd[j] = -1;
        if (e < E) {
            int d = dst[e];
            dd[j] = d;
            rk[j] = atomicAdd(&cnt[d >> BSH], 1);
        }
    }
    __syncthreads();
    if (cnt[tid]) sbase[tid] = atomicAdd(&bucket_fill[tid], cnt[tid]);
    __syncthreads();
#pragma unroll
    for (int j = 0; j < 16; j++) {
        int e = base + tid + j * 256;
        if (dd[j] >= 0) {
            int b = dd[j] >> BSH;
            int pos = sbase[b] + rk[j];
            bsrc[pos] = src[e];
            bdst[pos] = dd[j];
        }
    }
}

__global__ __launch_bounds__(256) void bfine_k(const int* __restrict__ bucket_off,
                                               const int* __restrict__ bsrc,
                                               const int* __restrict__ bdst,
                                               int* __restrict__ row_start,
                                               int* __restrict__ col, int N) {
    __shared__ int cnt[BSZ];
    __shared__ int off[BSZ];
    __shared__ int fill[BSZ];
    __shared__ int s[256];
    int tid = threadIdx.x;
    int b = blockIdx.x;
    int e0 = bucket_off[b], e1 = bucket_off[b + 1];
    int nbase = b << BSH;
    cnt[tid] = 0; cnt[tid + 256] = 0;
    fill[tid] = 0; fill[tid + 256] = 0;
    __syncthreads();
    for (int e = e0 + tid; e < e1; e += 256) atomicAdd(&cnt[bdst[e] - nbase], 1);
    __syncthreads();
    int a = cnt[2 * tid], bb = cnt[2 * tid + 1];
    s[tid] = a + bb;
    __syncthreads();
    for (int o = 1; o < 256; o <<= 1) {
        int t = 0;
        if (tid >= o) t = s[tid - o];
        __syncthreads();
        s[tid] += t;
        __syncthreads();
    }
    int excl = s[tid] - (a + bb);
    off[2 * tid] = excl;
    off[2 * tid + 1] = excl + a;
    __syncthreads();
    for (int i = tid; i < BSZ; i += 256) {
        int n = nbase + i;
        if (n < N) row_start[n] = e0 + off[i];
    }
    for (int e = e0 + tid; e < e1; e += 256) {
        int d = bdst[e];
        int loc = d - nbase;
        int sv = bsrc[e];
        int r = atomicAdd(&fill[loc], 1);
        col[e0 + off[loc] + r] = sv;
    }
}

// ---------------- message prep: marr = bf16(relu(x)+eps), x possibly BN-affined ----------------
template <int AFF>
__global__ __launch_bounds__(256) void prep_k(const float* __restrict__ in,
                                              const float* __restrict__ fa,
                                              const float* __restrict__ fc,
                                              ushort* __restrict__ marr, int total4) {
    int i = blockIdx.x * 256 + threadIdx.x;
    if (i >= total4) return;
    float4 v = ((const float4*)in)[i];
    int c0 = (i * 4) & 63;
    float vv[4] = {v.x, v.y, v.z, v.w};
    ushort u[4];
#pragma unroll
    for (int j = 0; j < 4; j++) {
        float x = vv[j];
        if (AFF) {
            float xv = fmaxf(x * fa[c0 + j] + fc[c0 + j], 0.f) + FEPS;
            x = xv + FEPS;
        } else {
            x = fmaxf(x, 0.f) + FEPS;
        }
        __hip_bfloat16 h = __float2bfloat16(x);
        u[j] = *reinterpret_cast<ushort*>(&h);
    }
    ushort4 uv = make_ushort4(u[0], u[1], u[2], u[3]);
    ((ushort4*)marr)[i] = uv;
}

// ---------------- fused softmax-aggregation + MessageNorm ----------------
// Quarter-wave edge parallelism: lane=(q,ql); quarter q handles edge e+q; lane owns
// channels 4ql..4ql+3 (one uint2 = 8B of the 128B bf16 row). Main loop keeps 4
// dwordx2 gathers (16 edges) in flight before computing -> 4-8x MLP vs round 7.
template <int MODE>
__global__ __launch_bounds__(256) void agg_k(const float* __restrict__ xin,
                                             const float* __restrict__ ta,
                                             const float* __restrict__ tc,
                                             const uint2* __restrict__ marr64,
                                             const int* __restrict__ rs,
                                             const int* __restrict__ col,
                                             const float* __restrict__ t,
                                             const float* __restrict__ sc,
                                             int layer, float* __restrict__ outb, int N) {
    int lane = threadIdx.x & 63;
    int wid = threadIdx.x >> 6;
    int n = blockIdx.x * 4 + wid;
    if (n >= N) return;
    int q = lane >> 4;      // quarter 0..3
    int ql = lane & 15;     // owns channels 4ql..4ql+3
    float tv = t[layer];
    float sv = sc[layer];

    int beg = rs[n], end = rs[n + 1];
    float den[4] = {0.f, 0.f, 0.f, 0.f}, num[4] = {0.f, 0.f, 0.f, 0.f};

    auto acc4 = [&](uint2 d) {
        float m0 = __uint_as_float(d.x << 16);
        float m1 = __uint_as_float(d.x & 0xffff0000u);
        float m2 = __uint_as_float(d.y << 16);
        float m3 = __uint_as_float(d.y & 0xffff0000u);
        float e0 = __expf(m0 * tv);
        float e1 = __expf(m1 * tv);
        float e2 = __expf(m2 * tv);
        float e3 = __expf(m3 * tv);
        den[0] += e0; num[0] += m0 * e0;
        den[1] += e1; num[1] += m1 * e1;
        den[2] += e2; num[2] += m2 * e2;
        den[3] += e3; num[3] += m3 * e3;
    };

    int e = beg;
    for (; e + 16 <= end; e += 16) {
        uint2 d0 = marr64[(size_t)col[e + q] * 16 + ql];
        uint2 d1 = marr64[(size_t)col[e + 4 + q] * 16 + ql];
        uint2 d2 = marr64[(size_t)col[e + 8 + q] * 16 + ql];
        uint2 d3 = marr64[(size_t)col[e + 12 + q] * 16 + ql];
        acc4(d0); acc4(d1); acc4(d2); acc4(d3);
    }
    for (; e + 4 <= end; e += 4) {
        uint2 d0 = marr64[(size_t)col[e + q] * 16 + ql];
        acc4(d0);
    }
    int rem = end - e;
    if (q < rem) {
        uint2 d0 = marr64[(size_t)col[e + q] * 16 + ql];
        acc4(d0);
    }

    // combine the 4 quarters (lane bits 4,5)
#pragma unroll
    for (int c = 0; c < 4; c++) {
        den[c] += __shfl_xor(den[c], 16, 64);
        den[c] += __shfl_xor(den[c], 32, 64);
        num[c] += __shfl_xor(num[c], 16, 64);
        num[c] += __shfl_xor(num[c], 32, 64);
    }
    float agg[4], aq = 0.f;
#pragma unroll
    for (int c = 0; c < 4; c++) {
        agg[c] = (den[c] > 0.f) ? (num[c] / den[c]) : 0.f;
        aq += agg[c] * agg[c];
    }

    float4 xv = ((const float4*)xin)[(size_t)n * 16 + ql];
    float xn[4];
    if (MODE == 0) {
        xn[0] = xv.x; xn[1] = xv.y; xn[2] = xv.z; xn[3] = xv.w;
    } else {
        float4 av = ((const float4*)ta)[ql];
        float4 cv = ((const float4*)tc)[ql];
        xn[0] = fmaxf(xv.x * av.x + cv.x, 0.f) + FEPS;
        xn[1] = fmaxf(xv.y * av.y + cv.y, 0.f) + FEPS;
        xn[2] = fmaxf(xv.z * av.z + cv.z, 0.f) + FEPS;
        xn[3] = fmaxf(xv.w * av.w + cv.w, 0.f) + FEPS;
    }
    float xq = xn[0] * xn[0] + xn[1] * xn[1] + xn[2] * xn[2] + xn[3] * xn[3];
    // each channel appears in all 4 quarters -> wave_sum counts 4x -> *0.25
    float na = wave_sum(aq) * 0.25f;
    float nx = wave_sum(xq) * 0.25f;
    float s = (1.0f / fmaxf(sqrtf(na), 1e-12f)) * sqrtf(nx) * sv;
    if (q == 0) {
        float4 o;
        o.x = xn[0] + agg[0] * s;
        o.y = xn[1] + agg[1] * s;
        o.z = xn[2] + agg[2] * s;
        o.w = xn[3] + agg[3] * s;
        ((float4*)outb)[(size_t)n * 16 + ql] = o;
    }
}

// ---------------- tiled MLP GEMM: out[N,ND] = act(A[N,KD]) @ W[KD,ND] + bias ----------------
template <int KD, int ND, int AFF>
__global__ __launch_bounds__(256) void mlp_k(const float* __restrict__ A,
                                             const float* __restrict__ fa,
                                             const float* __restrict__ fc,
                                             const float* __restrict__ Wg,
                                             const float* __restrict__ bias,
                                             float* __restrict__ outp,
                                             float* __restrict__ s_sum,
                                             float* __restrict__ s_ssq, int N) {
    constexpr int AST = KD + 4;           // padded A stride
    constexpr int NG = ND / 64;           // col groups of 4 per thread
    __shared__ float Ws[KD * ND];
    __shared__ float As[64 * AST];
    __shared__ float faf[AFF ? KD : 1][2];
    __shared__ float st[ND][2];

    int tid = threadIdx.x;
    for (int i = tid; i < KD * ND / 4; i += 256)
        ((float4*)Ws)[i] = ((const float4*)Wg)[i];
    if (AFF) {
        for (int i = tid; i < KD; i += 256) { faf[i][0] = fa[i]; faf[i][1] = fc[i]; }
    }
    if (tid < ND) { st[tid][0] = 0.f; st[tid][1] = 0.f; }
    __syncthreads();   // faf/st visible before A-tile staging uses them

    int base = blockIdx.x * 64;
    for (int e = tid; e < 64 * KD / 4; e += 256) {
        int row = e / (KD / 4);
        int kk = (e % (KD / 4)) * 4;
        float4 v = make_float4(0.f, 0.f, 0.f, 0.f);
        if (base + row < N) v = ((const float4*)A)[(size_t)(base + row) * (KD / 4) + (kk >> 2)];
        if (AFF) {
            v.x = fmaxf(v.x * faf[kk + 0][0] + faf[kk + 0][1], 0.f);
            v.y = fmaxf(v.y * faf[kk + 1][0] + faf[kk + 1][1], 0.f);
            v.z = fmaxf(v.z * faf[kk + 2][0] + faf[kk + 2][1], 0.f);
            v.w = fmaxf(v.w * faf[kk + 3][0] + faf[kk + 3][1], 0.f);
        }
        *(float4*)&As[row * AST + kk] = v;
    }
    __syncthreads();

    int ri = tid >> 4, ci = tid & 15;
    int r0 = ri * 4;
    float acc[4][NG][4];
#pragma unroll
    for (int j = 0; j < 4; j++)
#pragma unroll
        for (int g = 0; g < NG; g++)
#pragma unroll
            for (int c = 0; c < 4; c++) acc[j][g][c] = 0.f;

    for (int k4 = 0; k4 < KD / 4; k4++) {
        float av[4][4];
#pragma unroll
        for (int j = 0; j < 4; j++) {
            float4 t4 = *(const float4*)&As[(r0 + j) * AST + k4 * 4];
            av[j][0] = t4.x; av[j][1] = t4.y; av[j][2] = t4.z; av[j][3] = t4.w;
        }
#pragma unroll
        for (int kk = 0; kk < 4; kk++) {
            int k = k4 * 4 + kk;
#pragma unroll
            for (int g = 0; g < NG; g++) {
                float4 wv = *(const float4*)&Ws[k * ND + g * 64 + ci * 4];
#pragma unroll
                for (int j = 0; j < 4; j++) {
                    acc[j][g][0] += av[j][kk] * wv.x;
                    acc[j][g][1] += av[j][kk] * wv.y;
                    acc[j][g][2] += av[j][kk] * wv.z;
                    acc[j][g][3] += av[j][kk] * wv.w;
                }
            }
        }
    }

    float bb[NG][4];
#pragma unroll
    for (int g = 0; g < NG; g++) {
        float4 b4 = *(const float4*)&bias[g * 64 + ci * 4];
        bb[g][0] = b4.x; bb[g][1] = b4.y; bb[g][2] = b4.z; bb[g][3] = b4.w;
    }
    float ls[NG][4], lq[NG][4];
#pragma unroll
    for (int g = 0; g < NG; g++)
#pragma unroll
        for (int c = 0; c < 4; c++) { ls[g][c] = 0.f; lq[g][c] = 0.f; }

#pragma unroll
    for (int j = 0; j < 4; j++) {
        int row = base + r0 + j;
        if (row < N) {
#pragma unroll
            for (int g = 0; g < NG; g++) {
                float4 h4;
                h4.x = acc[j][g][0] + bb[g][0];
                h4.y = acc[j][g][1] + bb[g][1];
                h4.z = acc[j][g][2] + bb[g][2];
                h4.w = acc[j][g][3] + bb[g][3];
                *(float4*)&outp[(size_t)row * ND + g * 64 + ci * 4] = h4;
                ls[g][0] += h4.x; lq[g][0] += h4.x * h4.x;
                ls[g][1] += h4.y; lq[g][1] += h4.y * h4.y;
                ls[g][2] += h4.z; lq[g][2] += h4.z * h4.z;
                ls[g][3] += h4.w; lq[g][3] += h4.w * h4.w;
            }
        }
    }
#pragma unroll
    for (int g = 0; g < NG; g++)
#pragma unroll
        for (int c = 0; c < 4; c++) {
            atomicAdd(&st[g * 64 + ci * 4 + c][0], ls[g][c]);
            atomicAdd(&st[g * 64 + ci * 4 + c][1], lq[g][c]);
        }
    __syncthreads();
    if (tid < ND) {
        atomicAdd(&s_sum[tid], st[tid][0]);
        atomicAdd(&s_ssq[tid], st[tid][1]);
    }
}

// ---------------- BN finalize ----------------
__global__ void bnfin_k(const float* __restrict__ sum, const float* __restrict__ ssq,
                        const float* __restrict__ g, const float* __restrict__ b,
                        float* __restrict__ a, float* __restrict__ cc, int n, float invN) {
    int i = threadIdx.x;
    if (i < n) {
        float mu = sum[i] * invN;
        float var = ssq[i] * invN - mu * mu;
        float rs = rsqrtf(var + BNE);
        float gg = g[i];
        float bb = b[i];
        a[i] = rs * gg;
        cc[i] = bb - mu * rs * gg;
    }
}

// ---------------- final: out = relu(x0 + (y*a2+c2)) + eps (float4) ----------------
__global__ void final_k(const float4* __restrict__ x0, const float4* __restrict__ y,
                        const float* __restrict__ a2, const float* __restrict__ c2,
                        float4* __restrict__ outp, int total4) {
    int i = blockIdx.x * 256 + threadIdx.x;
    if (i >= total4) return;
    int c0 = (i * 4) & 63;
    float4 yv = y[i], xv = x0[i];
    float4 o;
    o.x = fmaxf(xv.x + yv.x * a2[c0 + 0] + c2[c0 + 0], 0.f) + FEPS;
    o.y = fmaxf(xv.y + yv.y * a2[c0 + 1] + c2[c0 + 1], 0.f) + FEPS;
    o.z = fmaxf(xv.z + yv.z * a2[c0 + 2] + c2[c0 + 2], 0.f) + FEPS;
    o.w = fmaxf(xv.w + yv.w * a2[c0 + 3] + c2[c0 + 3], 0.f) + FEPS;
    outp[i] = o;
}

extern "C" void kernel_launch(void* const* d_in, const int* in_sizes, int n_in,
                              void* d_out, int out_size, void* d_ws, size_t ws_size,
                              hipStream_t stream) {
    const float* x0 = (const float*)d_in[0];
    const int* ei = (const int*)d_in[1];
    const float* t = (const float*)d_in[2];
    const float* scale = (const float*)d_in[3];
    const float* W1 = (const float*)d_in[4];
    const float* b1 = (const float*)d_in[5];
    const float* g1 = (const float*)d_in[6];
    const float* be1 = (const float*)d_in[7];
    const float* W2 = (const float*)d_in[8];
    const float* b2 = (const float*)d_in[9];
    const float* bn_g = (const float*)d_in[10];
    const float* bn_b = (const float*)d_in[11];

    const int N = in_sizes[0] / C;
    const int E = in_sizes[1] / 2;
    const int* src = ei;
    const int* dst = ei + E;
    const int NB = (N + BSZ - 1) >> BSH;   // buckets (<=256 required)

    char* ws = (char*)d_ws;
    size_t cur = 0;
    auto alloc = [&](size_t bytes) -> char* {
        char* p = ws + cur;
        cur = (cur + bytes + 255) & ~(size_t)255;
        return p;
    };
    int* bucket_cnt = (int*)alloc(256 * 4);
    float* stats = (float*)alloc(768 * 4);          // [layer][sum1 128|ssq1 128|sum2 64|ssq2 64]
    size_t zbytes = cur;                            // zero only atomic targets
    float* params = (float*)alloc(768 * 4);         // [layer][a1 128|c1 128|a2 64|c2 64]
    int* bucket_off = (int*)alloc(257 * 4);
    int* bucket_fill = (int*)alloc(256 * 4);
    int* row_start = (int*)alloc(((size_t)N + 1) * 4);
    int* col = (int*)alloc((size_t)E * 4);
    ushort* marr = (ushort*)alloc((size_t)N * C * 2);   // bf16 messages
    float* bout = (float*)alloc((size_t)N * C * 4);
    float* bh = (float*)alloc((size_t)N * H * 4);
    float* by = (float*)alloc((size_t)N * C * 4);
    // bsrc/bdst alias bh: CSR build finishes before first mlp_k uses bh
    int* bsrc = (int*)bh;
    int* bdst = bsrc + E;

    hipMemsetAsync(d_ws, 0, zbytes, stream);

    // CSR build (bucketed)
    int nbE16 = (E + 4095) / 4096;
    bhist_k<<<nbE16, 256, 0, stream>>>(dst, bucket_cnt, E, NB);
    bscan_k<<<1, 256, 0, stream>>>(bucket_cnt, bucket_off, bucket_fill, row_start, NB, N, E);
    bscat_k<<<nbE16, 256, 0, stream>>>(src, dst, bucket_fill, bsrc, bdst, E);
    bfine_k<<<NB, 256, 0, stream>>>(bucket_off, bsrc, bdst, row_start, col, N);

    float* sum1_0 = stats + 0;   float* ssq1_0 = stats + 128;
    float* sum2_0 = stats + 256; float* ssq2_0 = stats + 320;
    float* sum1_1 = stats + 384; float* ssq1_1 = stats + 512;
    float* sum2_1 = stats + 640; float* ssq2_1 = stats + 704;
    float* a1_0 = params + 0;   float* c1_0 = params + 128;
    float* a2_0 = params + 256; float* c2_0 = params + 320;
    float* a1_1 = params + 384; float* c1_1 = params + 512;
    float* a2_1 = params + 640; float* c2_1 = params + 704;

    const float invN = 1.0f / (float)N;
    int nbN4 = (N + 3) / 4;
    int nbT = (N + 63) / 64;              // GEMM row tiles
    int nbP = (N * C / 4 + 255) / 256;    // prep/final (4 elems/thread)

    // ---- layer 0 ----
    prep_k<0><<<nbP, 256, 0, stream>>>(x0, nullptr, nullptr, marr, N * C / 4);
    agg_k<0><<<nbN4, 256, 0, stream>>>(x0, nullptr, nullptr,
                                       (const uint2*)marr, row_start, col,
                                       t, scale, 0, bout, N);
    mlp_k<C, H, 0><<<nbT, 256, 0, stream>>>(bout, nullptr, nullptr, W1, b1, bh, sum1_0, ssq1_0, N);
    bnfin_k<<<1, 128, 0, stream>>>(sum1_0, ssq1_0, g1, be1, a1_0, c1_0, H, invN);
    mlp_k<H, C, 1><<<nbT, 256, 0, stream>>>(bh, a1_0, c1_0, W2, b2, by, sum2_0, ssq2_0, N);
    bnfin_k<<<1, 64, 0, stream>>>(sum2_0, ssq2_0, bn_g, bn_b, a2_0, c2_0, C, invN);

    // ---- layer 1 ----
    prep_k<1><<<nbP, 256, 0, stream>>>(by, a2_0, c2_0, marr, N * C / 4);
    agg_k<1><<<nbN4, 256, 0, stream>>>(by, a2_0, c2_0,
                                       (const uint2*)marr, row_start, col,
                                       t, scale, 1, bout, N);
    mlp_k<C, H, 0><<<nbT, 256, 0, stream>>>(bout, nullptr, nullptr, W1 + C * H, b1 + H, bh, sum1_1, ssq1_1, N);
    bnfin_k<<<1, 128, 0, stream>>>(sum1_1, ssq1_1, g1 + H, be1 + H, a1_1, c1_1, H, invN);
    mlp_k<H, C, 1><<<nbT, 256, 0, stream>>>(bh, a1_1, c1_1, W2 + H * C, b2 + C, by, sum2_1, ssq2_1, N);
    bnfin_k<<<1, 64, 0, stream>>>(sum2_1, ssq2_1, bn_g + C, bn_b + C, a2_1, c2_1, C, invN);

    // ---- residual + relu + eps ----
    final_k<<<nbP, 256, 0, stream>>>((const float4*)x0, (const float4*)by, a2_1, c2_1,
                                     (float4*)d_out, N * C / 4);
}